// Round 2
// baseline (1866.185 us; speedup 1.0000x reference)
//
#include <hip/hip_runtime.h>
#include <hip/hip_bf16.h>
#include <stdint.h>

typedef __attribute__((ext_vector_type(8))) __bf16 bf16x8;
typedef __attribute__((ext_vector_type(8))) short short8;
typedef __attribute__((ext_vector_type(4))) float floatx4;
using bf16 = __hip_bfloat16;

#define DEVINL __device__ __forceinline__

typedef __attribute__((address_space(1))) const void gconst_void;
typedef __attribute__((address_space(3))) void lds_void;

DEVINL void gl2lds16(const void* g, void* l) {
    __builtin_amdgcn_global_load_lds((gconst_void*)g, (lds_void*)l, 16, 0, 0);
}

DEVINL unsigned short f2us(float x) {
    bf16 h = __float2bfloat16(x);
    return __builtin_bit_cast(unsigned short, h);
}
// flag==1: inputs are f32; flag==0: inputs are bf16
DEVINL float ld_in(const void* p, int f, size_t i) {
    return f ? ((const float*)p)[i] : __bfloat162float(((const bf16*)p)[i]);
}

// ---------------- dtype probe (confirmed: inputs are f32; keep hedge) ----------------
__global__ void detect_k(const void* x, int* flag) {
    if (threadIdx.x == 0) {
        const float* xf = (const float*)x;
        int good = 0;
        for (int i = 0; i < 64; i++) {
            float a = fabsf(xf[i]);
            if (a > 1e-8f && a < 100.f) good++;
        }
        *flag = (good >= 48) ? 1 : 0;
    }
}

// ---------------- prep kernels ----------------

__global__ void zero_border_k(bf16* buf, int C) {
    int cell = blockIdx.x;   // 0..259
    int b = blockIdx.y;
    int hp, wp;
    if (cell < 66)       { hp = 0;          wp = cell; }
    else if (cell < 132) { hp = 65;         wp = cell - 66; }
    else if (cell < 196) { hp = cell - 131; wp = 0; }
    else                 { hp = cell - 195; wp = 65; }
    unsigned short* p = (unsigned short*)buf + (size_t)(b * 4356 + hp * 66 + wp) * C;
    for (int c = threadIdx.x; c < C; c += 256) p[c] = 0;
}

// zero pad channels 1632..1663 of Xb for every cell (keeps MFMA inputs clean; weights there are 0)
__global__ void zero_chanpad_k(bf16* Xb, int n) {   // n = G*4356*4
    int idx = blockIdx.x * 256 + threadIdx.x;
    if (idx >= n) return;
    int cell = idx >> 2, sub = idx & 3;
    uint4 z; z.x = 0; z.y = 0; z.z = 0; z.w = 0;
    *(uint4*)((unsigned short*)Xb + (size_t)cell * 1664 + 1632 + sub * 8) = z;
}

__global__ void nchw_to_pnhwc_k(const void* __restrict__ src, bf16* __restrict__ dst,
                                const int* __restrict__ flag,
                                int Csrc, int dstC, int chanOff, int b0) {
    __shared__ unsigned short t[32][72];
    int c0 = blockIdx.x * 32, h = blockIdx.y, bz = blockIdx.z;
    int tid = threadIdx.x;
    {
        int c = tid >> 3, w8 = (tid & 7) * 8;
        size_t base = (((size_t)((b0 + bz) * Csrc + c0 + c)) * 64 + h) * 64 + w8;
        unsigned short* tp = &t[c][w8];
        if (*flag) {
            const float* sf = (const float*)src;
            float4 v0 = *(const float4*)(sf + base);
            float4 v1 = *(const float4*)(sf + base + 4);
            tp[0] = f2us(v0.x); tp[1] = f2us(v0.y); tp[2] = f2us(v0.z); tp[3] = f2us(v0.w);
            tp[4] = f2us(v1.x); tp[5] = f2us(v1.y); tp[6] = f2us(v1.z); tp[7] = f2us(v1.w);
        } else {
            uint4 v = *(const uint4*)((const unsigned short*)src + base);
            *(uint4*)tp = v;
        }
    }
    __syncthreads();
    {
        int w = tid >> 2, cq = (tid & 3) * 8;
        uint32_t p0 = t[cq + 0][w] | ((uint32_t)t[cq + 1][w] << 16);
        uint32_t p1 = t[cq + 2][w] | ((uint32_t)t[cq + 3][w] << 16);
        uint32_t p2 = t[cq + 4][w] | ((uint32_t)t[cq + 5][w] << 16);
        uint32_t p3 = t[cq + 6][w] | ((uint32_t)t[cq + 7][w] << 16);
        uint4 o; o.x = p0; o.y = p1; o.z = p2; o.w = p3;
        size_t off = ((size_t)(bz * 4356 + (h + 1) * 66 + (w + 1))) * dstC + chanOff + c0 + cq;
        *(uint4*)((unsigned short*)dst + off) = o;
    }
}

__global__ void raw_patches_k(const void* __restrict__ raw, bf16* __restrict__ Xa,
                              const int* __restrict__ flag, int b0) {
    __shared__ unsigned short t[8][520];
    int h = blockIdx.x, craw = blockIdx.y, bz = blockIdx.z;
    int tid = threadIdx.x;
    int f = *flag;
#pragma unroll
    for (int k = 0; k < 2; k++) {
        int s = tid + k * 256;
        int gy = s >> 6, seg = s & 63;
        size_t base = (((size_t)((b0 + bz) * 3 + craw) * 512) + gy * 64 + h) * 512 + seg * 8;
        unsigned short* tp = &t[gy][seg * 8];
        if (f) {
            const float* rf = (const float*)raw;
            float4 v0 = *(const float4*)(rf + base);
            float4 v1 = *(const float4*)(rf + base + 4);
            tp[0] = f2us(v0.x); tp[1] = f2us(v0.y); tp[2] = f2us(v0.z); tp[3] = f2us(v0.w);
            tp[4] = f2us(v1.x); tp[5] = f2us(v1.y); tp[6] = f2us(v1.z); tp[7] = f2us(v1.w);
        } else {
            uint4 v = *(const uint4*)((const unsigned short*)raw + base);
            *(uint4*)tp = v;
        }
    }
    __syncthreads();
#pragma unroll
    for (int k = 0; k < 2; k++) {
        int s = tid + k * 256;
        int w = s >> 3, gq = s & 7;
        uint32_t p0 = t[gq][0 * 64 + w] | ((uint32_t)t[gq][1 * 64 + w] << 16);
        uint32_t p1 = t[gq][2 * 64 + w] | ((uint32_t)t[gq][3 * 64 + w] << 16);
        uint32_t p2 = t[gq][4 * 64 + w] | ((uint32_t)t[gq][5 * 64 + w] << 16);
        uint32_t p3 = t[gq][6 * 64 + w] | ((uint32_t)t[gq][7 * 64 + w] << 16);
        uint4 o; o.x = p0; o.y = p1; o.z = p2; o.w = p3;
        size_t off = ((size_t)(bz * 4356 + (h + 1) * 66 + (w + 1))) * 576 + 384 + craw * 64 + gq * 8;
        *(uint4*)((unsigned short*)Xa + off) = o;
    }
}

// srcC = real input channels of the torch weight; dstC = padded K-stride of folded buffer.
// Output rows padded to 768 (rows 576..767 zero) so BN=384 tiles need no masking.
__global__ void fold_w_k(const void* __restrict__ W, bf16* __restrict__ dst,
                         const int* __restrict__ flag, int srcC, int dstC, int remap) {
    int ci = blockIdx.x * 256 + threadIdx.x;
    if (ci >= dstC) return;
    int co = blockIdx.y;  // 0..767
    int kk = blockIdx.z;  // 0..8
    unsigned short out = 0;
    if (co < 576 && ci < srcC) {
        int oc = ci;
        if (remap && ci >= 384) {
            int tt = ci - 384;
            int craw = tt >> 6, gy = (tt >> 3) & 7, gx = tt & 7;
            oc = 384 + gy * 24 + gx * 3 + craw;
        }
        size_t sidx = ((size_t)co * srcC + oc) * 9 + kk;
        out = (*flag) ? f2us(((const float*)W)[sidx]) : ((const unsigned short*)W)[sidx];
    }
    ((unsigned short*)dst)[((size_t)kk * 768 + co) * dstC + ci] = out;
}

__global__ void scale_beta_k(const void* g, const void* b, const void* m, const void* v,
                             const int* __restrict__ flag, float* inv_out, float* beta_out) {
    int i = blockIdx.x * 256 + threadIdx.x;
    int f = *flag;
    if (i < 576) {
        float inv = ld_in(g, f, i) / sqrtf(ld_in(v, f, i) + 1e-5f);
        inv_out[i] = inv;
        beta_out[i] = ld_in(b, f, i) - ld_in(m, f, i) * inv;
    }
}

// ---------------- 3x3 conv, implicit GEMM ----------------
// BM=128 BN=384 BK=64, 512 thr / 8 waves (2M x 4N, wave tile 64x96, acc 4x6).
// FLOP/LDS-byte = 38.4 -> LDS-BW cap ~93% (round-1's 64x32 waves capped at ~43%).
// Double-buffered 128 KB LDS (1 block/CU, 2 waves/SIMD), counted s_waitcnt
// vmcnt(8) pipeline (next K-tile's 8 global_load_lds stay in flight across
// barriers; never drained in steady state), T2 XOR swizzle (0 conflicts,
// verified r1), T5 setprio, T1 XCD-contiguous swizzle. K flattened over
// 9 taps x Cin (Cin % 64 == 0; cc pads 1632->1664). N padded 640->768 so
// grid = mtiles*2 (exact multiple of 256 CUs at G=8: 512 blocks).
__global__ __launch_bounds__(512, 2)
void conv3x3_mfma(const bf16* __restrict__ X, const bf16* __restrict__ Wp,
                  const float* __restrict__ inv, const float* __restrict__ beta,
                  bf16* __restrict__ dst, int Cin, int dstC, int chanOff, int dstPadded,
                  int mtiles) {
    __shared__ __align__(16) bf16 Alds[2][8192];    // 2 x 16 KB (128 rows x 64)
    __shared__ __align__(16) bf16 Blds[2][24576];   // 2 x 48 KB (384 rows x 64)
    const int tid = threadIdx.x;
    const int wv = tid >> 6;
    const int lane = tid & 63;
    const int quad = lane >> 4;
    const int r16 = lane & 15;

    // T1: XCD-contiguous remap (nwg = mtiles*2 is always % 8 == 0).
    // Consecutive wg in one XCD: same weight panel, adjacent A row-tiles.
    const int nwg = gridDim.x;
    const int wg = ((int)blockIdx.x & 7) * (nwg >> 3) + ((int)blockIdx.x >> 3);
    const int m0 = (wg % mtiles) * 128;
    const int n0 = (wg / mtiles) * 384;

    // staging: 512 thr x 16B = 8 KB = 64 rows per gl2lds; A: 2 loads, B: 6 loads
    const int rl = tid >> 3;                          // 0..63
    const int cg = ((tid & 7) ^ (rl & 7)) * 8;        // inverse-swizzled source chunk (halfwords)
    int aF[2], bF[6];
#pragma unroll
    for (int q = 0; q < 2; q++) {
        int r = m0 + rl + 64 * q;
        int bb = r >> 12, hh = (r >> 6) & 63, ww = r & 63;
        aF[q] = (bb * 4356 + (hh + 1) * 66 + (ww + 1)) * Cin + cg;
    }
#pragma unroll
    for (int q = 0; q < 6; q++) bF[q] = (n0 + rl + 64 * q) * Cin + cg;

    // fragment-read geometry (wave tile 64x96: 4 M-frags x 6 N-frags)
    const int wvM = wv >> 2, wvN = wv & 3;
    int aOff[4], bOff[6];
#pragma unroll
    for (int i = 0; i < 4; i++) aOff[i] = (wvM * 64 + i * 16 + r16) * 64;
#pragma unroll
    for (int j = 0; j < 6; j++) bOff[j] = (wvN * 96 + j * 16 + r16) * 64;
    const int sw0 = (quad ^ (r16 & 7)) * 8;           // swizzled chunk, kq=0
    const int sw1 = ((quad + 4) ^ (r16 & 7)) * 8;     // swizzled chunk, kq=1

    // epilogue scale/shift loaded BEFORE the K-loop: keeps the main loop's
    // vmcnt population exactly = the gl2lds queue (counted waits stay exact).
    int ncol[6]; float sj[6], bj[6]; bool nval[6];
#pragma unroll
    for (int j = 0; j < 6; j++) {
        ncol[j] = n0 + wvN * 96 + j * 16 + r16;
        nval[j] = ncol[j] < 576;
        sj[j] = nval[j] ? inv[ncol[j]] : 0.f;
        bj[j] = nval[j] ? beta[ncol[j]] : 0.f;
    }
    asm volatile("s_waitcnt vmcnt(0)" ::: "memory");  // drain sj/bj loads before pipeline starts

    floatx4 acc[4][6];
    floatx4 zero = {0.f, 0.f, 0.f, 0.f};
#pragma unroll
    for (int i = 0; i < 4; i++)
#pragma unroll
        for (int j = 0; j < 6; j++) acc[i][j] = zero;

    auto compute = [&](const bf16* Ab, const bf16* Bb) {
#pragma unroll
        for (int kq = 0; kq < 2; kq++) {
            const int sw = kq ? sw1 : sw0;
            short8 af[4], bfr[6];
#pragma unroll
            for (int i = 0; i < 4; i++) af[i] = *(const short8*)(Ab + aOff[i] + sw);
#pragma unroll
            for (int j = 0; j < 6; j++) bfr[j] = *(const short8*)(Bb + bOff[j] + sw);
            __builtin_amdgcn_s_setprio(1);
#pragma unroll
            for (int i = 0; i < 4; i++)
#pragma unroll
                for (int j = 0; j < 6; j++)
                    acc[i][j] = __builtin_amdgcn_mfma_f32_16x16x32_bf16(
                        __builtin_bit_cast(bf16x8, af[i]), __builtin_bit_cast(bf16x8, bfr[j]),
                        acc[i][j], 0, 0, 0);
            __builtin_amdgcn_s_setprio(0);
        }
    };

    // flat K bookkeeping: (kkN, ciN) = coordinates of the NEXT tile to stage
    int kkN = 0, ciN = 0, tapOffN = -67 * Cin, wbN = 0;   // tap 0: dh=-1,dw=-1
#define STAGE(pn) do { \
        bf16* al_ = Alds[pn] + wv * 512; \
        bf16* bl_ = Blds[pn] + wv * 512; \
        const int so_ = tapOffN + ciN; \
        const int wo_ = wbN + ciN; \
        gl2lds16(X + aF[0] + so_, al_); \
        gl2lds16(X + aF[1] + so_, al_ + 4096); \
        gl2lds16(Wp + bF[0] + wo_, bl_); \
        gl2lds16(Wp + bF[1] + wo_, bl_ + 4096); \
        gl2lds16(Wp + bF[2] + wo_, bl_ + 8192); \
        gl2lds16(Wp + bF[3] + wo_, bl_ + 12288); \
        gl2lds16(Wp + bF[4] + wo_, bl_ + 16384); \
        gl2lds16(Wp + bF[5] + wo_, bl_ + 20480); \
    } while (0)
#define ADV() do { ciN += 64; if (ciN == Cin) { ciN = 0; ++kkN; \
        tapOffN = ((kkN / 3) * 66 + (kkN % 3) - 67) * Cin; wbN += 768 * Cin; } } while (0)

    STAGE(0);
    ADV();
    const int NT = 9 * (Cin >> 6);
    int p = 0;
    for (int t = 0; t < NT - 1; ++t, p ^= 1) {
        STAGE(p ^ 1);                 // issue next tile's 8 loads FIRST (stay in flight)
        ADV();
        // wait only for the CURRENT tile's 8 loads (8 newer ones outstanding)
        asm volatile("s_waitcnt vmcnt(8)\n\ts_barrier" ::: "memory");
        compute(Alds[p], Blds[p]);
        __builtin_amdgcn_s_barrier(); // all reads of buf p done before t+2 overwrites it
    }
    asm volatile("s_waitcnt vmcnt(0)\n\ts_barrier" ::: "memory");
    compute(Alds[p], Blds[p]);
#undef STAGE
#undef ADV

    // epilogue: D[row=quad*4+r, col=lane&15] (verified m89/m91 layout)
#pragma unroll
    for (int i = 0; i < 4; i++) {
#pragma unroll
        for (int r = 0; r < 4; r++) {
            int row = m0 + wvM * 64 + i * 16 + quad * 4 + r;
            int didx;
            if (dstPadded) {
                int bb = row >> 12, hh = (row >> 6) & 63, ww = row & 63;
                didx = (bb * 4356 + (hh + 1) * 66 + (ww + 1)) * dstC + chanOff;
            } else {
                didx = row * dstC + chanOff;
            }
#pragma unroll
            for (int j = 0; j < 6; j++)
                if (nval[j]) dst[didx + ncol[j]] = __float2bfloat16(acc[i][j][r] * sj[j] + bj[j]);
        }
    }
}

// ---------------- tail: 1x1 conv (576->1) + x8 bilinear upsample ----------------
__global__ void o2_dot_k(const bf16* __restrict__ Y, const void* __restrict__ w,
                         const void* __restrict__ bias, const int* __restrict__ flag,
                         float* __restrict__ smap) {
    __shared__ float wl[576];
    int tid = threadIdx.x;
    int f = *flag;
    for (int c = tid; c < 576; c += 256) wl[c] = ld_in(w, f, c);
    __syncthreads();
    int wv = tid >> 6, lane = tid & 63;
    int pix = blockIdx.x * 4 + wv;
    const bf16* yp = Y + (size_t)pix * 576;
    float s = 0.f;
#pragma unroll
    for (int k = 0; k < 9; k++) {
        int c = k * 64 + lane;
        s += __bfloat162float(yp[c]) * wl[c];
    }
#pragma unroll
    for (int off = 32; off; off >>= 1) s += __shfl_xor(s, off, 64);
    if (lane == 0) smap[pix] = s + ld_in(bias, f, 0);
}

__global__ void upsample_k(const float* __restrict__ smap, void* __restrict__ out,
                           const int* __restrict__ flag) {
    int idx = blockIdx.x * 256 + threadIdx.x;   // 8*512*512 exact
    int b = idx >> 18;
    int ho = (idx >> 9) & 511;
    int wo = idx & 511;
    const float sc = 63.f / 511.f;              // align_corners=True
    float ys = ho * sc, xs = wo * sc;
    int y0 = (int)ys; float ty = ys - y0; int y1 = min(y0 + 1, 63);
    int x0 = (int)xs; float tx = xs - x0; int x1 = min(x0 + 1, 63);
    const float* sp = smap + (b << 12);
    float r0 = sp[y0 * 64 + x0] * (1.f - tx) + sp[y0 * 64 + x1] * tx;
    float r1 = sp[y1 * 64 + x0] * (1.f - tx) + sp[y1 * 64 + x1] * tx;
    float val = r0 * (1.f - ty) + r1 * ty;
    if (*flag) ((float*)out)[idx] = val;
    else       ((bf16*)out)[idx] = __float2bfloat16(val);
}

// ---------------- launch ----------------
extern "C" void kernel_launch(void* const* d_in, const int* in_sizes, int n_in,
                              void* d_out, int out_size, void* d_ws, size_t ws_size,
                              hipStream_t stream) {
    const void* coarse = d_in[0];
    const void* x22    = d_in[1];
    const void* x31    = d_in[2];
    const void* rawx   = d_in[3];
    // d_in[4]=w_pred, d_in[5]=b_pred : dead code in reference
    const void* dec_w = d_in[6];
    const void *dec_g = d_in[7], *dec_b = d_in[8], *dec_m = d_in[9], *dec_v = d_in[10];
    const void* cc_w = d_in[11];
    const void *cc_g = d_in[12], *cc_b = d_in[13], *cc_m = d_in[14], *cc_v = d_in[15];
    const void* o1_w = d_in[16];
    const void *o1_g = d_in[17], *o1_b = d_in[18], *o1_m = d_in[19], *o1_v = d_in[20];
    const void* o2_w = d_in[21];
    const void* o2_b = d_in[22];

    // adaptive chunk ladder (weights padded to 768 output rows, cc K-pad 1632->1664)
    const size_t wcc_sz  = (size_t)9 * 768 * 1664 * 2;
    const size_t wsm_sz  = (size_t)9 * 768 * 576 * 2;
    const size_t tail_sz = 16384 + 131072 + 256;
    int G = 8; int sepW = 1;
    for (;;) {
        size_t acts = (size_t)G * 4356 * (576 + 1664) * 2;
        if (acts + wcc_sz + 2 * wsm_sz + tail_sz <= ws_size) { sepW = 1; break; }
        if (acts + wcc_sz + tail_sz <= ws_size)              { sepW = 0; break; }
        if (G == 1) { sepW = 0; break; }
        G >>= 1;
    }
    size_t xa_sz = (size_t)G * 4356 * 576 * 2;
    size_t xb_sz = (size_t)G * 4356 * 1664 * 2;

    char* ws = (char*)d_ws;
    bf16* Xa   = (bf16*)(ws);
    bf16* Xb   = (bf16*)(ws + xa_sz);
    bf16* Wcc  = (bf16*)(ws + xa_sz + xb_sz);
    bf16* Wdec = sepW ? (bf16*)(ws + xa_sz + xb_sz + wcc_sz) : Wcc;
    bf16* Wo1  = sepW ? (bf16*)(ws + xa_sz + xb_sz + wcc_sz + wsm_sz) : Wcc;
    size_t wtot = wcc_sz + (sepW ? 2 * wsm_sz : 0);
    float* sb  = (float*)(ws + xa_sz + xb_sz + wtot);
    float* invDec = sb,        *betaDec = sb + 576;
    float* invCc  = sb + 1152, *betaCc  = sb + 1728;
    float* invO1  = sb + 2304, *betaO1  = sb + 2880;
    float* smap = (float*)(ws + xa_sz + xb_sz + wtot + 16384);
    int* flag   = (int*)(ws + xa_sz + xb_sz + wtot + 16384 + 131072);
    bf16* Yo1q = Xb;

    detect_k<<<1, 64, 0, stream>>>(coarse, flag);
    scale_beta_k<<<3, 256, 0, stream>>>(dec_g, dec_b, dec_m, dec_v, flag, invDec, betaDec);
    scale_beta_k<<<3, 256, 0, stream>>>(cc_g, cc_b, cc_m, cc_v, flag, invCc, betaCc);
    scale_beta_k<<<3, 256, 0, stream>>>(o1_g, o1_b, o1_m, o1_v, flag, invO1, betaO1);
    if (sepW) {
        fold_w_k<<<dim3(3, 768, 9), 256, 0, stream>>>(dec_w, Wdec, flag, 576, 576, 1);
        fold_w_k<<<dim3(7, 768, 9), 256, 0, stream>>>(cc_w, Wcc, flag, 1632, 1664, 0);
        fold_w_k<<<dim3(3, 768, 9), 256, 0, stream>>>(o1_w, Wo1, flag, 576, 576, 0);
    }

    const int nchunk = 8 / G;
    const int mt = G * 32;                 // 128-row M-tiles per chunk
    for (int q = 0; q < nchunk; q++) {
        const int b0 = q * G;
        zero_border_k<<<dim3(260, G), 256, 0, stream>>>(Xa, 576);
        zero_border_k<<<dim3(260, G), 256, 0, stream>>>(Xb, 1664);
        zero_chanpad_k<<<(G * 4356 * 4 + 255) / 256, 256, 0, stream>>>(Xb, G * 4356 * 4);
        nchw_to_pnhwc_k<<<dim3(12, 64, G), 256, 0, stream>>>(coarse, Xa, flag, 384, 576, 0, b0);
        raw_patches_k<<<dim3(64, 3, G), 256, 0, stream>>>(rawx, Xa, flag, b0);
        nchw_to_pnhwc_k<<<dim3(24, 64, G), 256, 0, stream>>>(x22, Xb, flag, 768, 1664, 0, b0);
        nchw_to_pnhwc_k<<<dim3(9, 64, G), 256, 0, stream>>>(x31, Xb, flag, 288, 1664, 1344, b0);
        if (!sepW) fold_w_k<<<dim3(3, 768, 9), 256, 0, stream>>>(dec_w, Wdec, flag, 576, 576, 1);
        conv3x3_mfma<<<dim3(mt * 2), 512, 0, stream>>>(Xa, Wdec, invDec, betaDec, Xb, 576, 1664, 768, 1, mt);
        if (!sepW) fold_w_k<<<dim3(7, 768, 9), 256, 0, stream>>>(cc_w, Wcc, flag, 1632, 1664, 0);
        conv3x3_mfma<<<dim3(mt * 2), 512, 0, stream>>>(Xb, Wcc, invCc, betaCc, Xa, 1664, 576, 0, 1, mt);
        if (!sepW) fold_w_k<<<dim3(3, 768, 9), 256, 0, stream>>>(o1_w, Wo1, flag, 576, 576, 0);
        conv3x3_mfma<<<dim3(mt * 2), 512, 0, stream>>>(Xa, Wo1, invO1, betaO1, Yo1q, 576, 576, 0, 0, mt);
        o2_dot_k<<<G * 1024, 256, 0, stream>>>(Yo1q, o2_w, o2_b, flag, smap + (size_t)q * G * 4096);
    }
    upsample_k<<<8192, 256, 0, stream>>>(smap, d_out, flag);
}

// Round 3
// 1530.816 us; speedup vs baseline: 1.2191x; 1.2191x over previous
//
#include <hip/hip_runtime.h>
#include <hip/hip_bf16.h>
#include <stdint.h>

typedef __attribute__((ext_vector_type(8))) __bf16 bf16x8;
typedef __attribute__((ext_vector_type(8))) short short8;
typedef __attribute__((ext_vector_type(4))) float floatx4;
using bf16 = __hip_bfloat16;

#define DEVINL __device__ __forceinline__

typedef __attribute__((address_space(1))) const void gconst_void;
typedef __attribute__((address_space(3))) void lds_void;

DEVINL void gl2lds16(const void* g, void* l) {
    __builtin_amdgcn_global_load_lds((gconst_void*)g, (lds_void*)l, 16, 0, 0);
}

DEVINL unsigned short f2us(float x) {
    bf16 h = __float2bfloat16(x);
    return __builtin_bit_cast(unsigned short, h);
}
// flag==1: inputs are f32; flag==0: inputs are bf16
DEVINL float ld_in(const void* p, int f, size_t i) {
    return f ? ((const float*)p)[i] : __bfloat162float(((const bf16*)p)[i]);
}

// ---------------- dtype probe (confirmed: inputs are f32; keep hedge) ----------------
__global__ void detect_k(const void* x, int* flag) {
    if (threadIdx.x == 0) {
        const float* xf = (const float*)x;
        int good = 0;
        for (int i = 0; i < 64; i++) {
            float a = fabsf(xf[i]);
            if (a > 1e-8f && a < 100.f) good++;
        }
        *flag = (good >= 48) ? 1 : 0;
    }
}

// ---------------- prep kernels ----------------

__global__ void zero_border_k(bf16* buf, int C) {
    int cell = blockIdx.x;   // 0..259
    int b = blockIdx.y;
    int hp, wp;
    if (cell < 66)       { hp = 0;          wp = cell; }
    else if (cell < 132) { hp = 65;         wp = cell - 66; }
    else if (cell < 196) { hp = cell - 131; wp = 0; }
    else                 { hp = cell - 195; wp = 65; }
    unsigned short* p = (unsigned short*)buf + (size_t)(b * 4356 + hp * 66 + wp) * C;
    for (int c = threadIdx.x; c < C; c += 256) p[c] = 0;
}

// zero pad channels 1632..1663 of Xb for every cell (keeps MFMA inputs clean; weights there are 0)
__global__ void zero_chanpad_k(bf16* Xb, int n) {   // n = G*4356*4
    int idx = blockIdx.x * 256 + threadIdx.x;
    if (idx >= n) return;
    int cell = idx >> 2, sub = idx & 3;
    uint4 z; z.x = 0; z.y = 0; z.z = 0; z.w = 0;
    *(uint4*)((unsigned short*)Xb + (size_t)cell * 1664 + 1632 + sub * 8) = z;
}

__global__ void nchw_to_pnhwc_k(const void* __restrict__ src, bf16* __restrict__ dst,
                                const int* __restrict__ flag,
                                int Csrc, int dstC, int chanOff, int b0) {
    __shared__ unsigned short t[32][72];
    int c0 = blockIdx.x * 32, h = blockIdx.y, bz = blockIdx.z;
    int tid = threadIdx.x;
    {
        int c = tid >> 3, w8 = (tid & 7) * 8;
        size_t base = (((size_t)((b0 + bz) * Csrc + c0 + c)) * 64 + h) * 64 + w8;
        unsigned short* tp = &t[c][w8];
        if (*flag) {
            const float* sf = (const float*)src;
            float4 v0 = *(const float4*)(sf + base);
            float4 v1 = *(const float4*)(sf + base + 4);
            tp[0] = f2us(v0.x); tp[1] = f2us(v0.y); tp[2] = f2us(v0.z); tp[3] = f2us(v0.w);
            tp[4] = f2us(v1.x); tp[5] = f2us(v1.y); tp[6] = f2us(v1.z); tp[7] = f2us(v1.w);
        } else {
            uint4 v = *(const uint4*)((const unsigned short*)src + base);
            *(uint4*)tp = v;
        }
    }
    __syncthreads();
    {
        int w = tid >> 2, cq = (tid & 3) * 8;
        uint32_t p0 = t[cq + 0][w] | ((uint32_t)t[cq + 1][w] << 16);
        uint32_t p1 = t[cq + 2][w] | ((uint32_t)t[cq + 3][w] << 16);
        uint32_t p2 = t[cq + 4][w] | ((uint32_t)t[cq + 5][w] << 16);
        uint32_t p3 = t[cq + 6][w] | ((uint32_t)t[cq + 7][w] << 16);
        uint4 o; o.x = p0; o.y = p1; o.z = p2; o.w = p3;
        size_t off = ((size_t)(bz * 4356 + (h + 1) * 66 + (w + 1))) * dstC + chanOff + c0 + cq;
        *(uint4*)((unsigned short*)dst + off) = o;
    }
}

__global__ void raw_patches_k(const void* __restrict__ raw, bf16* __restrict__ Xa,
                              const int* __restrict__ flag, int b0) {
    __shared__ unsigned short t[8][520];
    int h = blockIdx.x, craw = blockIdx.y, bz = blockIdx.z;
    int tid = threadIdx.x;
    int f = *flag;
#pragma unroll
    for (int k = 0; k < 2; k++) {
        int s = tid + k * 256;
        int gy = s >> 6, seg = s & 63;
        size_t base = (((size_t)((b0 + bz) * 3 + craw) * 512) + gy * 64 + h) * 512 + seg * 8;
        unsigned short* tp = &t[gy][seg * 8];
        if (f) {
            const float* rf = (const float*)raw;
            float4 v0 = *(const float4*)(rf + base);
            float4 v1 = *(const float4*)(rf + base + 4);
            tp[0] = f2us(v0.x); tp[1] = f2us(v0.y); tp[2] = f2us(v0.z); tp[3] = f2us(v0.w);
            tp[4] = f2us(v1.x); tp[5] = f2us(v1.y); tp[6] = f2us(v1.z); tp[7] = f2us(v1.w);
        } else {
            uint4 v = *(const uint4*)((const unsigned short*)raw + base);
            *(uint4*)tp = v;
        }
    }
    __syncthreads();
#pragma unroll
    for (int k = 0; k < 2; k++) {
        int s = tid + k * 256;
        int w = s >> 3, gq = s & 7;
        uint32_t p0 = t[gq][0 * 64 + w] | ((uint32_t)t[gq][1 * 64 + w] << 16);
        uint32_t p1 = t[gq][2 * 64 + w] | ((uint32_t)t[gq][3 * 64 + w] << 16);
        uint32_t p2 = t[gq][4 * 64 + w] | ((uint32_t)t[gq][5 * 64 + w] << 16);
        uint32_t p3 = t[gq][6 * 64 + w] | ((uint32_t)t[gq][7 * 64 + w] << 16);
        uint4 o; o.x = p0; o.y = p1; o.z = p2; o.w = p3;
        size_t off = ((size_t)(bz * 4356 + (h + 1) * 66 + (w + 1))) * 576 + 384 + craw * 64 + gq * 8;
        *(uint4*)((unsigned short*)Xa + off) = o;
    }
}

// srcC = real input channels of the torch weight; dstC = padded K-stride of folded buffer.
// Output rows padded to 640 (rows 576..639 zero) -> 2 exact BN=320 tiles.
__global__ void fold_w_k(const void* __restrict__ W, bf16* __restrict__ dst,
                         const int* __restrict__ flag, int srcC, int dstC, int remap) {
    int ci = blockIdx.x * 256 + threadIdx.x;
    if (ci >= dstC) return;
    int co = blockIdx.y;  // 0..639
    int kk = blockIdx.z;  // 0..8
    unsigned short out = 0;
    if (co < 576 && ci < srcC) {
        int oc = ci;
        if (remap && ci >= 384) {
            int tt = ci - 384;
            int craw = tt >> 6, gy = (tt >> 3) & 7, gx = tt & 7;
            oc = 384 + gy * 24 + gx * 3 + craw;
        }
        size_t sidx = ((size_t)co * srcC + oc) * 9 + kk;
        out = (*flag) ? f2us(((const float*)W)[sidx]) : ((const unsigned short*)W)[sidx];
    }
    ((unsigned short*)dst)[((size_t)kk * 640 + co) * dstC + ci] = out;
}

__global__ void scale_beta_k(const void* g, const void* b, const void* m, const void* v,
                             const int* __restrict__ flag, float* inv_out, float* beta_out) {
    int i = blockIdx.x * 256 + threadIdx.x;
    int f = *flag;
    if (i < 576) {
        float inv = ld_in(g, f, i) / sqrtf(ld_in(v, f, i) + 1e-5f);
        inv_out[i] = inv;
        beta_out[i] = ld_in(b, f, i) - ld_in(m, f, i) * inv;
    }
}

// ---------------- 3x3 conv, implicit GEMM, m201-style 4-phase schedule ----------------
// BM=256 BN=320 BK=64, 512 thr / 8 waves (2M x 4N, wave tile 128x80, acc 8x5).
// Grid = mtiles*2 = 256 blocks at G=8 -> exactly 1 block/CU, no tail, N=640 exact.
// Per K-tile: 4 phases (M-half x kq). Each phase: 9 ds_read_b128 + issue 3 gl2lds
// chunks of tile t+1 + barrier + 20-MFMA setprio cluster + barrier (m201 rhythm:
// loads spread across phases, issued 2-4 phases before use). ONE counted wait per
// K-tile: vmcnt(3) at phase 0 -- never drains in steady state (T3+T4). T2 XOR
// swizzle both-sides (0 conflicts, verified r1/r2). T5 setprio. T1 XCD swizzle.
__global__ __launch_bounds__(512, 2)
void conv3x3_mfma(const bf16* __restrict__ X, const bf16* __restrict__ Wp,
                  const float* __restrict__ inv, const float* __restrict__ beta,
                  bf16* __restrict__ dst, int Cin, int dstC, int chanOff, int dstPadded,
                  int mtiles) {
    __shared__ __align__(16) bf16 Alds[2 * 16384];   // 2 x 32 KB : [256 rows][64]
    __shared__ __align__(16) bf16 Blds[2 * 20480];   // 2 x 40 KB : [320 rows][64]
    const int tid = threadIdx.x;
    const int wv = tid >> 6;
    const int lane = tid & 63;
    const int quad = lane >> 4;
    const int r16 = lane & 15;

    // T1: XCD-contiguous remap (nwg = 32*G, always % 8 == 0)
    const int nwg = gridDim.x;
    const int wg = ((int)blockIdx.x & 7) * (nwg >> 3) + ((int)blockIdx.x >> 3);
    const int m0 = (wg % mtiles) * 256;
    const int n0 = (wg / mtiles) * 320;

    // staging: each 64-row chunk = 8 KB = one gl2lds across 512 threads
    const int rl = tid >> 3;                          // 0..63 (row within chunk)
    const int cg = ((tid & 7) ^ (rl & 7)) * 8;        // inverse-swizzled source chunk (halfwords)
    int aF[4], bF[5];
#pragma unroll
    for (int q = 0; q < 4; q++) {
        int r = m0 + q * 64 + rl;
        int bb = r >> 12, hh = (r >> 6) & 63;
        aF[q] = (bb * 4356 + (hh + 1) * 66 + (rl + 1)) * Cin + cg;
    }
#pragma unroll
    for (int q = 0; q < 5; q++) bF[q] = (n0 + q * 64 + rl) * Cin + cg;

    // fragment-read geometry (wave tile 128x80: 8 M-frags x 5 N-frags)
    const int wvM = wv >> 2, wvN = wv & 3;
    int aOff[8], bOff[5];
#pragma unroll
    for (int i = 0; i < 8; i++) aOff[i] = (wvM * 128 + i * 16 + r16) * 64;
#pragma unroll
    for (int j = 0; j < 5; j++) bOff[j] = (wvN * 80 + j * 16 + r16) * 64;
    const int sw0 = (quad ^ (r16 & 7)) * 8;           // swizzled chunk, kq=0
    const int sw1 = ((quad + 4) ^ (r16 & 7)) * 8;     // swizzled chunk, kq=1

    floatx4 acc[8][5];
    floatx4 zero = {0.f, 0.f, 0.f, 0.f};
#pragma unroll
    for (int i = 0; i < 8; i++)
#pragma unroll
        for (int j = 0; j < 5; j++) acc[i][j] = zero;

#define BAR() asm volatile("s_barrier" ::: "memory")
#define READS(h, sw) do { \
    _Pragma("unroll") for (int i_ = 0; i_ < 4; i_++) \
        af[i_] = *(const short8*)(Ap + aOff[(h) * 4 + i_] + (sw)); \
    _Pragma("unroll") for (int j_ = 0; j_ < 5; j_++) \
        bfr[j_] = *(const short8*)(Bp + bOff[j_] + (sw)); } while (0)
#define MM(h) do { \
    __builtin_amdgcn_s_setprio(1); \
    _Pragma("unroll") for (int i_ = 0; i_ < 4; i_++) \
    _Pragma("unroll") for (int j_ = 0; j_ < 5; j_++) \
        acc[(h) * 4 + i_][j_] = __builtin_amdgcn_mfma_f32_16x16x32_bf16( \
            __builtin_bit_cast(bf16x8, af[i_]), __builtin_bit_cast(bf16x8, bfr[j_]), \
            acc[(h) * 4 + i_][j_], 0, 0, 0); \
    __builtin_amdgcn_s_setprio(0); } while (0)
#define GA(q) gl2lds16(X + aF[q] + so, Ao + (q) * 4096 + wv * 512)
#define GB(q) gl2lds16(Wp + bF[q] + wo, Bo + (q) * 4096 + wv * 512)
#define ADV() do { ciN += 64; if (ciN == Cin) { ciN = 0; ++kkN; \
        tapOffN = ((kkN / 3) * 66 + (kkN % 3) - 67) * Cin; wbN += 640 * Cin; } } while (0)

    // flat K bookkeeping: (kkN, ciN) = coordinates of the NEXT tile to stage
    int kkN = 0, ciN = 0, tapOffN = -67 * Cin, wbN = 0;   // tap 0: dh=-1,dw=-1
    {   // prologue: stage tile 0 fully into buf 0
        const int so = tapOffN + ciN, wo = wbN + ciN;
        bf16* Ao = Alds; bf16* Bo = Blds;
        GA(0); GA(1); GA(2); GA(3);
        GB(0); GB(1); GB(2); GB(3); GB(4);
    }
    ADV();
    const int NT = 9 * (Cin >> 6);
    int p = 0;
    for (int t = 0; t < NT - 1; ++t, p ^= 1) {
        const bf16* Ap = Alds + p * 16384;
        const bf16* Bp = Blds + p * 20480;
        bf16* Ao = Alds + (p ^ 1) * 16384;
        bf16* Bo = Blds + (p ^ 1) * 20480;
        const int so = tapOffN + ciN, wo = wbN + ciN;
        short8 af[4], bfr[5];
        // phase 0 (M-half 0, kq 0): issue 3, counted wait, validity barrier
        GA(0); GA(1); GA(2);
        asm volatile("s_waitcnt vmcnt(3)" ::: "memory");
        BAR();
        READS(0, sw0);
        MM(0);
        BAR();
        // phase 1 (M-half 0, kq 1)
        READS(0, sw1);
        GA(3); GB(0); GB(1);
        BAR();
        MM(0);
        BAR();
        // phase 2 (M-half 1, kq 0)
        READS(1, sw0);
        GB(2); GB(3); GB(4);
        BAR();
        MM(1);
        BAR();
        // phase 3 (M-half 1, kq 1)
        READS(1, sw1);
        BAR();
        MM(1);
        BAR();
        ADV();
    }
    {   // last tile: nothing newer outstanding -> one-time full drain
        const bf16* Ap = Alds + p * 16384;
        const bf16* Bp = Blds + p * 20480;
        short8 af[4], bfr[5];
        asm volatile("s_waitcnt vmcnt(0)" ::: "memory");
        BAR();
        READS(0, sw0); MM(0); BAR();
        READS(0, sw1); BAR(); MM(0); BAR();
        READS(1, sw0); BAR(); MM(1); BAR();
        READS(1, sw1); BAR(); MM(1);
    }
#undef BAR
#undef READS
#undef MM
#undef GA
#undef GB
#undef ADV

    // epilogue (loads kept OUT of the loop so vmcnt counting stays exact):
    // D[row=quad*4+r, col=lane&15] (verified m89/m91 layout)
    int ncol[5]; float sj[5], bj[5]; bool nval[5];
#pragma unroll
    for (int j = 0; j < 5; j++) {
        ncol[j] = n0 + wvN * 80 + j * 16 + r16;
        nval[j] = ncol[j] < 576;
        sj[j] = nval[j] ? inv[ncol[j]] : 0.f;
        bj[j] = nval[j] ? beta[ncol[j]] : 0.f;
    }
#pragma unroll
    for (int i = 0; i < 8; i++) {
#pragma unroll
        for (int r = 0; r < 4; r++) {
            int row = m0 + wvM * 128 + i * 16 + quad * 4 + r;
            int didx;
            if (dstPadded) {
                int bb = row >> 12, hh = (row >> 6) & 63, ww = row & 63;
                didx = (bb * 4356 + (hh + 1) * 66 + (ww + 1)) * dstC + chanOff;
            } else {
                didx = row * dstC + chanOff;
            }
#pragma unroll
            for (int j = 0; j < 5; j++)
                if (nval[j]) dst[didx + ncol[j]] = __float2bfloat16(acc[i][j][r] * sj[j] + bj[j]);
        }
    }
}

// ---------------- tail: 1x1 conv (576->1) + x8 bilinear upsample ----------------
__global__ void o2_dot_k(const bf16* __restrict__ Y, const void* __restrict__ w,
                         const void* __restrict__ bias, const int* __restrict__ flag,
                         float* __restrict__ smap) {
    __shared__ float wl[576];
    int tid = threadIdx.x;
    int f = *flag;
    for (int c = tid; c < 576; c += 256) wl[c] = ld_in(w, f, c);
    __syncthreads();
    int wv = tid >> 6, lane = tid & 63;
    int pix = blockIdx.x * 4 + wv;
    const bf16* yp = Y + (size_t)pix * 576;
    float s = 0.f;
#pragma unroll
    for (int k = 0; k < 9; k++) {
        int c = k * 64 + lane;
        s += __bfloat162float(yp[c]) * wl[c];
    }
#pragma unroll
    for (int off = 32; off; off >>= 1) s += __shfl_xor(s, off, 64);
    if (lane == 0) smap[pix] = s + ld_in(bias, f, 0);
}

__global__ void upsample_k(const float* __restrict__ smap, void* __restrict__ out,
                           const int* __restrict__ flag) {
    int idx = blockIdx.x * 256 + threadIdx.x;   // 8*512*512 exact
    int b = idx >> 18;
    int ho = (idx >> 9) & 511;
    int wo = idx & 511;
    const float sc = 63.f / 511.f;              // align_corners=True
    float ys = ho * sc, xs = wo * sc;
    int y0 = (int)ys; float ty = ys - y0; int y1 = min(y0 + 1, 63);
    int x0 = (int)xs; float tx = xs - x0; int x1 = min(x0 + 1, 63);
    const float* sp = smap + (b << 12);
    float r0 = sp[y0 * 64 + x0] * (1.f - tx) + sp[y0 * 64 + x1] * tx;
    float r1 = sp[y1 * 64 + x0] * (1.f - tx) + sp[y1 * 64 + x1] * tx;
    float val = r0 * (1.f - ty) + r1 * ty;
    if (*flag) ((float*)out)[idx] = val;
    else       ((bf16*)out)[idx] = __float2bfloat16(val);
}

// ---------------- launch ----------------
extern "C" void kernel_launch(void* const* d_in, const int* in_sizes, int n_in,
                              void* d_out, int out_size, void* d_ws, size_t ws_size,
                              hipStream_t stream) {
    const void* coarse = d_in[0];
    const void* x22    = d_in[1];
    const void* x31    = d_in[2];
    const void* rawx   = d_in[3];
    // d_in[4]=w_pred, d_in[5]=b_pred : dead code in reference
    const void* dec_w = d_in[6];
    const void *dec_g = d_in[7], *dec_b = d_in[8], *dec_m = d_in[9], *dec_v = d_in[10];
    const void* cc_w = d_in[11];
    const void *cc_g = d_in[12], *cc_b = d_in[13], *cc_m = d_in[14], *cc_v = d_in[15];
    const void* o1_w = d_in[16];
    const void *o1_g = d_in[17], *o1_b = d_in[18], *o1_m = d_in[19], *o1_v = d_in[20];
    const void* o2_w = d_in[21];
    const void* o2_b = d_in[22];

    // adaptive chunk ladder (weights: 640 output rows; cc K-pad 1632->1664)
    const size_t wcc_sz  = (size_t)9 * 640 * 1664 * 2;
    const size_t wsm_sz  = (size_t)9 * 640 * 576 * 2;
    const size_t tail_sz = 16384 + 131072 + 256;
    int G = 8; int sepW = 1;
    for (;;) {
        size_t acts = (size_t)G * 4356 * (576 + 1664) * 2;
        if (acts + wcc_sz + 2 * wsm_sz + tail_sz <= ws_size) { sepW = 1; break; }
        if (acts + wcc_sz + tail_sz <= ws_size)              { sepW = 0; break; }
        if (G == 1) { sepW = 0; break; }
        G >>= 1;
    }
    size_t xa_sz = (size_t)G * 4356 * 576 * 2;
    size_t xb_sz = (size_t)G * 4356 * 1664 * 2;

    char* ws = (char*)d_ws;
    bf16* Xa   = (bf16*)(ws);
    bf16* Xb   = (bf16*)(ws + xa_sz);
    bf16* Wcc  = (bf16*)(ws + xa_sz + xb_sz);
    bf16* Wdec = sepW ? (bf16*)(ws + xa_sz + xb_sz + wcc_sz) : Wcc;
    bf16* Wo1  = sepW ? (bf16*)(ws + xa_sz + xb_sz + wcc_sz + wsm_sz) : Wcc;
    size_t wtot = wcc_sz + (sepW ? 2 * wsm_sz : 0);
    float* sb  = (float*)(ws + xa_sz + xb_sz + wtot);
    float* invDec = sb,        *betaDec = sb + 576;
    float* invCc  = sb + 1152, *betaCc  = sb + 1728;
    float* invO1  = sb + 2304, *betaO1  = sb + 2880;
    float* smap = (float*)(ws + xa_sz + xb_sz + wtot + 16384);
    int* flag   = (int*)(ws + xa_sz + xb_sz + wtot + 16384 + 131072);
    bf16* Yo1q = Xb;

    detect_k<<<1, 64, 0, stream>>>(coarse, flag);
    scale_beta_k<<<3, 256, 0, stream>>>(dec_g, dec_b, dec_m, dec_v, flag, invDec, betaDec);
    scale_beta_k<<<3, 256, 0, stream>>>(cc_g, cc_b, cc_m, cc_v, flag, invCc, betaCc);
    scale_beta_k<<<3, 256, 0, stream>>>(o1_g, o1_b, o1_m, o1_v, flag, invO1, betaO1);
    if (sepW) {
        fold_w_k<<<dim3(3, 640, 9), 256, 0, stream>>>(dec_w, Wdec, flag, 576, 576, 1);
        fold_w_k<<<dim3(7, 640, 9), 256, 0, stream>>>(cc_w, Wcc, flag, 1632, 1664, 0);
        fold_w_k<<<dim3(3, 640, 9), 256, 0, stream>>>(o1_w, Wo1, flag, 576, 576, 0);
    }

    const int nchunk = 8 / G;
    const int mt = G * 16;                 // 256-row M-tiles per chunk
    for (int q = 0; q < nchunk; q++) {
        const int b0 = q * G;
        zero_border_k<<<dim3(260, G), 256, 0, stream>>>(Xa, 576);
        zero_border_k<<<dim3(260, G), 256, 0, stream>>>(Xb, 1664);
        zero_chanpad_k<<<(G * 4356 * 4 + 255) / 256, 256, 0, stream>>>(Xb, G * 4356 * 4);
        nchw_to_pnhwc_k<<<dim3(12, 64, G), 256, 0, stream>>>(coarse, Xa, flag, 384, 576, 0, b0);
        raw_patches_k<<<dim3(64, 3, G), 256, 0, stream>>>(rawx, Xa, flag, b0);
        nchw_to_pnhwc_k<<<dim3(24, 64, G), 256, 0, stream>>>(x22, Xb, flag, 768, 1664, 0, b0);
        nchw_to_pnhwc_k<<<dim3(9, 64, G), 256, 0, stream>>>(x31, Xb, flag, 288, 1664, 1344, b0);
        if (!sepW) fold_w_k<<<dim3(3, 640, 9), 256, 0, stream>>>(dec_w, Wdec, flag, 576, 576, 1);
        conv3x3_mfma<<<dim3(mt * 2), 512, 0, stream>>>(Xa, Wdec, invDec, betaDec, Xb, 576, 1664, 768, 1, mt);
        if (!sepW) fold_w_k<<<dim3(7, 640, 9), 256, 0, stream>>>(cc_w, Wcc, flag, 1632, 1664, 0);
        conv3x3_mfma<<<dim3(mt * 2), 512, 0, stream>>>(Xb, Wcc, invCc, betaCc, Xa, 1664, 576, 0, 1, mt);
        if (!sepW) fold_w_k<<<dim3(3, 640, 9), 256, 0, stream>>>(o1_w, Wo1, flag, 576, 576, 0);
        conv3x3_mfma<<<dim3(mt * 2), 512, 0, stream>>>(Xa, Wo1, invO1, betaO1, Yo1q, 576, 576, 0, 0, mt);
        o2_dot_k<<<G * 1024, 256, 0, stream>>>(Yo1q, o2_w, o2_b, flag, smap + (size_t)q * G * 4096);
    }
    upsample_k<<<8192, 256, 0, stream>>>(smap, d_out, flag);
}

// Round 4
// 1418.604 us; speedup vs baseline: 1.3155x; 1.0791x over previous
//
#include <hip/hip_runtime.h>
#include <hip/hip_bf16.h>
#include <stdint.h>

typedef __attribute__((ext_vector_type(8))) __bf16 bf16x8;
typedef __attribute__((ext_vector_type(8))) short short8;
typedef __attribute__((ext_vector_type(4))) float floatx4;
using bf16 = __hip_bfloat16;

#define DEVINL __device__ __forceinline__

typedef __attribute__((address_space(1))) const void gconst_void;
typedef __attribute__((address_space(3))) void lds_void;

DEVINL void gl2lds16(const void* g, void* l) {
    __builtin_amdgcn_global_load_lds((gconst_void*)g, (lds_void*)l, 16, 0, 0);
}

DEVINL unsigned short f2us(float x) {
    bf16 h = __float2bfloat16(x);
    return __builtin_bit_cast(unsigned short, h);
}
// flag==1: inputs are f32; flag==0: inputs are bf16
DEVINL float ld_in(const void* p, int f, size_t i) {
    return f ? ((const float*)p)[i] : __bfloat162float(((const bf16*)p)[i]);
}

// ---------------- dtype probe (confirmed: inputs are f32; keep hedge) ----------------
__global__ void detect_k(const void* x, int* flag) {
    if (threadIdx.x == 0) {
        const float* xf = (const float*)x;
        int good = 0;
        for (int i = 0; i < 64; i++) {
            float a = fabsf(xf[i]);
            if (a > 1e-8f && a < 100.f) good++;
        }
        *flag = (good >= 48) ? 1 : 0;
    }
}

// ---------------- prep kernels ----------------

__global__ void zero_border_k(bf16* buf, int C) {
    int cell = blockIdx.x;   // 0..259
    int b = blockIdx.y;
    int hp, wp;
    if (cell < 66)       { hp = 0;          wp = cell; }
    else if (cell < 132) { hp = 65;         wp = cell - 66; }
    else if (cell < 196) { hp = cell - 131; wp = 0; }
    else                 { hp = cell - 195; wp = 65; }
    unsigned short* p = (unsigned short*)buf + (size_t)(b * 4356 + hp * 66 + wp) * C;
    for (int c = threadIdx.x; c < C; c += 256) p[c] = 0;
}

// zero pad channels 1632..1663 of Xb for every cell (keeps MFMA inputs clean; weights there are 0)
__global__ void zero_chanpad_k(bf16* Xb, int n) {   // n = G*4356*4
    int idx = blockIdx.x * 256 + threadIdx.x;
    if (idx >= n) return;
    int cell = idx >> 2, sub = idx & 3;
    uint4 z; z.x = 0; z.y = 0; z.z = 0; z.w = 0;
    *(uint4*)((unsigned short*)Xb + (size_t)cell * 1664 + 1632 + sub * 8) = z;
}

__global__ void nchw_to_pnhwc_k(const void* __restrict__ src, bf16* __restrict__ dst,
                                const int* __restrict__ flag,
                                int Csrc, int dstC, int chanOff, int b0) {
    __shared__ unsigned short t[32][72];
    int c0 = blockIdx.x * 32, h = blockIdx.y, bz = blockIdx.z;
    int tid = threadIdx.x;
    {
        int c = tid >> 3, w8 = (tid & 7) * 8;
        size_t base = (((size_t)((b0 + bz) * Csrc + c0 + c)) * 64 + h) * 64 + w8;
        unsigned short* tp = &t[c][w8];
        if (*flag) {
            const float* sf = (const float*)src;
            float4 v0 = *(const float4*)(sf + base);
            float4 v1 = *(const float4*)(sf + base + 4);
            tp[0] = f2us(v0.x); tp[1] = f2us(v0.y); tp[2] = f2us(v0.z); tp[3] = f2us(v0.w);
            tp[4] = f2us(v1.x); tp[5] = f2us(v1.y); tp[6] = f2us(v1.z); tp[7] = f2us(v1.w);
        } else {
            uint4 v = *(const uint4*)((const unsigned short*)src + base);
            *(uint4*)tp = v;
        }
    }
    __syncthreads();
    {
        int w = tid >> 2, cq = (tid & 3) * 8;
        uint32_t p0 = t[cq + 0][w] | ((uint32_t)t[cq + 1][w] << 16);
        uint32_t p1 = t[cq + 2][w] | ((uint32_t)t[cq + 3][w] << 16);
        uint32_t p2 = t[cq + 4][w] | ((uint32_t)t[cq + 5][w] << 16);
        uint32_t p3 = t[cq + 6][w] | ((uint32_t)t[cq + 7][w] << 16);
        uint4 o; o.x = p0; o.y = p1; o.z = p2; o.w = p3;
        size_t off = ((size_t)(bz * 4356 + (h + 1) * 66 + (w + 1))) * dstC + chanOff + c0 + cq;
        *(uint4*)((unsigned short*)dst + off) = o;
    }
}

__global__ void raw_patches_k(const void* __restrict__ raw, bf16* __restrict__ Xa,
                              const int* __restrict__ flag, int b0) {
    __shared__ unsigned short t[8][520];
    int h = blockIdx.x, craw = blockIdx.y, bz = blockIdx.z;
    int tid = threadIdx.x;
    int f = *flag;
#pragma unroll
    for (int k = 0; k < 2; k++) {
        int s = tid + k * 256;
        int gy = s >> 6, seg = s & 63;
        size_t base = (((size_t)((b0 + bz) * 3 + craw) * 512) + gy * 64 + h) * 512 + seg * 8;
        unsigned short* tp = &t[gy][seg * 8];
        if (f) {
            const float* rf = (const float*)raw;
            float4 v0 = *(const float4*)(rf + base);
            float4 v1 = *(const float4*)(rf + base + 4);
            tp[0] = f2us(v0.x); tp[1] = f2us(v0.y); tp[2] = f2us(v0.z); tp[3] = f2us(v0.w);
            tp[4] = f2us(v1.x); tp[5] = f2us(v1.y); tp[6] = f2us(v1.z); tp[7] = f2us(v1.w);
        } else {
            uint4 v = *(const uint4*)((const unsigned short*)raw + base);
            *(uint4*)tp = v;
        }
    }
    __syncthreads();
#pragma unroll
    for (int k = 0; k < 2; k++) {
        int s = tid + k * 256;
        int w = s >> 3, gq = s & 7;
        uint32_t p0 = t[gq][0 * 64 + w] | ((uint32_t)t[gq][1 * 64 + w] << 16);
        uint32_t p1 = t[gq][2 * 64 + w] | ((uint32_t)t[gq][3 * 64 + w] << 16);
        uint32_t p2 = t[gq][4 * 64 + w] | ((uint32_t)t[gq][5 * 64 + w] << 16);
        uint32_t p3 = t[gq][6 * 64 + w] | ((uint32_t)t[gq][7 * 64 + w] << 16);
        uint4 o; o.x = p0; o.y = p1; o.z = p2; o.w = p3;
        size_t off = ((size_t)(bz * 4356 + (h + 1) * 66 + (w + 1))) * 576 + 384 + craw * 64 + gq * 8;
        *(uint4*)((unsigned short*)Xa + off) = o;
    }
}

// srcC = real input channels of the torch weight; dstC = padded K-stride of folded buffer.
// Output rows padded to 640 (rows 576..639 zero) -> 2 exact BN=320 tiles.
__global__ void fold_w_k(const void* __restrict__ W, bf16* __restrict__ dst,
                         const int* __restrict__ flag, int srcC, int dstC, int remap) {
    int ci = blockIdx.x * 256 + threadIdx.x;
    if (ci >= dstC) return;
    int co = blockIdx.y;  // 0..639
    int kk = blockIdx.z;  // 0..8
    unsigned short out = 0;
    if (co < 576 && ci < srcC) {
        int oc = ci;
        if (remap && ci >= 384) {
            int tt = ci - 384;
            int craw = tt >> 6, gy = (tt >> 3) & 7, gx = tt & 7;
            oc = 384 + gy * 24 + gx * 3 + craw;
        }
        size_t sidx = ((size_t)co * srcC + oc) * 9 + kk;
        out = (*flag) ? f2us(((const float*)W)[sidx]) : ((const unsigned short*)W)[sidx];
    }
    ((unsigned short*)dst)[((size_t)kk * 640 + co) * dstC + ci] = out;
}

__global__ void scale_beta_k(const void* g, const void* b, const void* m, const void* v,
                             const int* __restrict__ flag, float* inv_out, float* beta_out) {
    int i = blockIdx.x * 256 + threadIdx.x;
    int f = *flag;
    if (i < 576) {
        float inv = ld_in(g, f, i) / sqrtf(ld_in(v, f, i) + 1e-5f);
        inv_out[i] = inv;
        beta_out[i] = ld_in(b, f, i) - ld_in(m, f, i) * inv;
    }
}

// ---------------- 3x3 conv, implicit GEMM, 4-phase schedule, B-held-in-regs ----------------
// BM=256 BN=320 BK=64, 512 thr / 8 waves (2M x 4N, wave tile 128x80, acc 8x5).
// Phases per K-tile re-partitioned vs r3: (B+A(h0) -> MM(h0)), (A(h1) -> MM(h1))
// per kq, holding the 5 B-frags in registers across both M-halves. 26 LDS reads
// per K-tile per wave (geometric minimum) vs r3's 36 -- r3 was LDS-read-bound
// (read time 288 cyc/phase vs MFMA 194). Sync structure identical to passing r3:
// one counted vmcnt(3) per K-tile, 2 barriers/phase, T2 XOR swizzle both-sides,
// T5 setprio, T1 XCD swizzle, gl2lds spread 3+3+3 over phases 0-2.
__global__ __launch_bounds__(512, 2)
void conv3x3_mfma(const bf16* __restrict__ X, const bf16* __restrict__ Wp,
                  const float* __restrict__ inv, const float* __restrict__ beta,
                  bf16* __restrict__ dst, int Cin, int dstC, int chanOff, int dstPadded,
                  int mtiles) {
    __shared__ __align__(16) bf16 Alds[2 * 16384];   // 2 x 32 KB : [256 rows][64]
    __shared__ __align__(16) bf16 Blds[2 * 20480];   // 2 x 40 KB : [320 rows][64]
    const int tid = threadIdx.x;
    const int wv = tid >> 6;
    const int lane = tid & 63;
    const int quad = lane >> 4;
    const int r16 = lane & 15;

    // T1: XCD-contiguous remap (nwg = 32*G, always % 8 == 0)
    const int nwg = gridDim.x;
    const int wg = ((int)blockIdx.x & 7) * (nwg >> 3) + ((int)blockIdx.x >> 3);
    const int m0 = (wg % mtiles) * 256;
    const int n0 = (wg / mtiles) * 320;

    // staging: each 64-row chunk = 8 KB = one gl2lds across 512 threads
    const int rl = tid >> 3;                          // 0..63 (row within chunk)
    const int cg = ((tid & 7) ^ (rl & 7)) * 8;        // inverse-swizzled source chunk (halfwords)
    int aF[4], bF[5];
#pragma unroll
    for (int q = 0; q < 4; q++) {
        int r = m0 + q * 64 + rl;
        int bb = r >> 12, hh = (r >> 6) & 63;
        aF[q] = (bb * 4356 + (hh + 1) * 66 + (rl + 1)) * Cin + cg;
    }
#pragma unroll
    for (int q = 0; q < 5; q++) bF[q] = (n0 + q * 64 + rl) * Cin + cg;

    // fragment-read geometry (wave tile 128x80: 8 M-frags x 5 N-frags)
    const int wvM = wv >> 2, wvN = wv & 3;
    int aOff[8], bOff[5];
#pragma unroll
    for (int i = 0; i < 8; i++) aOff[i] = (wvM * 128 + i * 16 + r16) * 64;
#pragma unroll
    for (int j = 0; j < 5; j++) bOff[j] = (wvN * 80 + j * 16 + r16) * 64;
    const int sw0 = (quad ^ (r16 & 7)) * 8;           // swizzled chunk, kq=0
    const int sw1 = ((quad + 4) ^ (r16 & 7)) * 8;     // swizzled chunk, kq=1

    floatx4 acc[8][5];
    floatx4 zero = {0.f, 0.f, 0.f, 0.f};
#pragma unroll
    for (int i = 0; i < 8; i++)
#pragma unroll
        for (int j = 0; j < 5; j++) acc[i][j] = zero;

#define BAR() asm volatile("s_barrier" ::: "memory")
#define READB(sw) do { \
    _Pragma("unroll") for (int j_ = 0; j_ < 5; j_++) \
        bfr[j_] = *(const short8*)(Bp + bOff[j_] + (sw)); } while (0)
#define READA(h, sw) do { \
    _Pragma("unroll") for (int i_ = 0; i_ < 4; i_++) \
        af[i_] = *(const short8*)(Ap + aOff[(h) * 4 + i_] + (sw)); } while (0)
#define MM(h) do { \
    __builtin_amdgcn_s_setprio(1); \
    _Pragma("unroll") for (int i_ = 0; i_ < 4; i_++) \
    _Pragma("unroll") for (int j_ = 0; j_ < 5; j_++) \
        acc[(h) * 4 + i_][j_] = __builtin_amdgcn_mfma_f32_16x16x32_bf16( \
            __builtin_bit_cast(bf16x8, af[i_]), __builtin_bit_cast(bf16x8, bfr[j_]), \
            acc[(h) * 4 + i_][j_], 0, 0, 0); \
    __builtin_amdgcn_s_setprio(0); } while (0)
#define GA(q) gl2lds16(X + aF[q] + so, Ao + (q) * 4096 + wv * 512)
#define GB(q) gl2lds16(Wp + bF[q] + wo, Bo + (q) * 4096 + wv * 512)
#define ADV() do { ciN += 64; if (ciN == Cin) { ciN = 0; ++kkN; \
        tapOffN = ((kkN / 3) * 66 + (kkN % 3) - 67) * Cin; wbN += 640 * Cin; } } while (0)

    // flat K bookkeeping: (kkN, ciN) = coordinates of the NEXT tile to stage
    int kkN = 0, ciN = 0, tapOffN = -67 * Cin, wbN = 0;   // tap 0: dh=-1,dw=-1
    {   // prologue: stage tile 0 fully into buf 0
        const int so = tapOffN + ciN, wo = wbN + ciN;
        bf16* Ao = Alds; bf16* Bo = Blds;
        GA(0); GA(1); GA(2); GA(3);
        GB(0); GB(1); GB(2); GB(3); GB(4);
    }
    ADV();
    const int NT = 9 * (Cin >> 6);
    int p = 0;
    for (int t = 0; t < NT - 1; ++t, p ^= 1) {
        const bf16* Ap = Alds + p * 16384;
        const bf16* Bp = Blds + p * 20480;
        bf16* Ao = Alds + (p ^ 1) * 16384;
        bf16* Bo = Blds + (p ^ 1) * 20480;
        const int so = tapOffN + ciN, wo = wbN + ciN;
        short8 af[4], bfr[5];
        // phase 0 (kq0: B + A-half 0): issue 3, counted wait, validity barrier
        GA(0); GA(1); GA(2);
        asm volatile("s_waitcnt vmcnt(3)" ::: "memory");
        BAR();
        READB(sw0); READA(0, sw0);
        MM(0);
        BAR();
        // phase 1 (kq0: A-half 1, B held in regs)
        READA(1, sw0);
        GA(3); GB(0); GB(1);
        BAR();
        MM(1);
        BAR();
        // phase 2 (kq1: B + A-half 0)
        READB(sw1); READA(0, sw1);
        GB(2); GB(3); GB(4);
        BAR();
        MM(0);
        BAR();
        // phase 3 (kq1: A-half 1, B held in regs)
        READA(1, sw1);
        BAR();
        MM(1);
        BAR();
        ADV();
    }
    {   // last tile: nothing newer outstanding -> one-time full drain
        const bf16* Ap = Alds + p * 16384;
        const bf16* Bp = Blds + p * 20480;
        short8 af[4], bfr[5];
        asm volatile("s_waitcnt vmcnt(0)" ::: "memory");
        BAR();
        READB(sw0); READA(0, sw0); MM(0); BAR();
        READA(1, sw0); BAR(); MM(1); BAR();
        READB(sw1); READA(0, sw1); BAR(); MM(0); BAR();
        READA(1, sw1); BAR(); MM(1);
    }
#undef BAR
#undef READB
#undef READA
#undef MM
#undef GA
#undef GB
#undef ADV

    // epilogue (loads kept OUT of the loop so vmcnt counting stays exact):
    // D[row=quad*4+r, col=lane&15] (verified m89/m91 layout)
    int ncol[5]; float sj[5], bj[5]; bool nval[5];
#pragma unroll
    for (int j = 0; j < 5; j++) {
        ncol[j] = n0 + wvN * 80 + j * 16 + r16;
        nval[j] = ncol[j] < 576;
        sj[j] = nval[j] ? inv[ncol[j]] : 0.f;
        bj[j] = nval[j] ? beta[ncol[j]] : 0.f;
    }
#pragma unroll
    for (int i = 0; i < 8; i++) {
#pragma unroll
        for (int r = 0; r < 4; r++) {
            int row = m0 + wvM * 128 + i * 16 + quad * 4 + r;
            int didx;
            if (dstPadded) {
                int bb = row >> 12, hh = (row >> 6) & 63, ww = row & 63;
                didx = (bb * 4356 + (hh + 1) * 66 + (ww + 1)) * dstC + chanOff;
            } else {
                didx = row * dstC + chanOff;
            }
#pragma unroll
            for (int j = 0; j < 5; j++)
                if (nval[j]) dst[didx + ncol[j]] = __float2bfloat16(acc[i][j][r] * sj[j] + bj[j]);
        }
    }
}

// ---------------- tail: 1x1 conv (576->1) + x8 bilinear upsample ----------------
__global__ void o2_dot_k(const bf16* __restrict__ Y, const void* __restrict__ w,
                         const void* __restrict__ bias, const int* __restrict__ flag,
                         float* __restrict__ smap) {
    __shared__ float wl[576];
    int tid = threadIdx.x;
    int f = *flag;
    for (int c = tid; c < 576; c += 256) wl[c] = ld_in(w, f, c);
    __syncthreads();
    int wv = tid >> 6, lane = tid & 63;
    int pix = blockIdx.x * 4 + wv;
    const bf16* yp = Y + (size_t)pix * 576;
    float s = 0.f;
#pragma unroll
    for (int k = 0; k < 9; k++) {
        int c = k * 64 + lane;
        s += __bfloat162float(yp[c]) * wl[c];
    }
#pragma unroll
    for (int off = 32; off; off >>= 1) s += __shfl_xor(s, off, 64);
    if (lane == 0) smap[pix] = s + ld_in(bias, f, 0);
}

__global__ void upsample_k(const float* __restrict__ smap, void* __restrict__ out,
                           const int* __restrict__ flag) {
    int idx = blockIdx.x * 256 + threadIdx.x;   // 8*512*512 exact
    int b = idx >> 18;
    int ho = (idx >> 9) & 511;
    int wo = idx & 511;
    const float sc = 63.f / 511.f;              // align_corners=True
    float ys = ho * sc, xs = wo * sc;
    int y0 = (int)ys; float ty = ys - y0; int y1 = min(y0 + 1, 63);
    int x0 = (int)xs; float tx = xs - x0; int x1 = min(x0 + 1, 63);
    const float* sp = smap + (b << 12);
    float r0 = sp[y0 * 64 + x0] * (1.f - tx) + sp[y0 * 64 + x1] * tx;
    float r1 = sp[y1 * 64 + x0] * (1.f - tx) + sp[y1 * 64 + x1] * tx;
    float val = r0 * (1.f - ty) + r1 * ty;
    if (*flag) ((float*)out)[idx] = val;
    else       ((bf16*)out)[idx] = __float2bfloat16(val);
}

// ---------------- launch ----------------
extern "C" void kernel_launch(void* const* d_in, const int* in_sizes, int n_in,
                              void* d_out, int out_size, void* d_ws, size_t ws_size,
                              hipStream_t stream) {
    const void* coarse = d_in[0];
    const void* x22    = d_in[1];
    const void* x31    = d_in[2];
    const void* rawx   = d_in[3];
    // d_in[4]=w_pred, d_in[5]=b_pred : dead code in reference
    const void* dec_w = d_in[6];
    const void *dec_g = d_in[7], *dec_b = d_in[8], *dec_m = d_in[9], *dec_v = d_in[10];
    const void* cc_w = d_in[11];
    const void *cc_g = d_in[12], *cc_b = d_in[13], *cc_m = d_in[14], *cc_v = d_in[15];
    const void* o1_w = d_in[16];
    const void *o1_g = d_in[17], *o1_b = d_in[18], *o1_m = d_in[19], *o1_v = d_in[20];
    const void* o2_w = d_in[21];
    const void* o2_b = d_in[22];

    // adaptive chunk ladder (weights: 640 output rows; cc K-pad 1632->1664)
    const size_t wcc_sz  = (size_t)9 * 640 * 1664 * 2;
    const size_t wsm_sz  = (size_t)9 * 640 * 576 * 2;
    const size_t tail_sz = 16384 + 131072 + 256;
    int G = 8; int sepW = 1;
    for (;;) {
        size_t acts = (size_t)G * 4356 * (576 + 1664) * 2;
        if (acts + wcc_sz + 2 * wsm_sz + tail_sz <= ws_size) { sepW = 1; break; }
        if (acts + wcc_sz + tail_sz <= ws_size)              { sepW = 0; break; }
        if (G == 1) { sepW = 0; break; }
        G >>= 1;
    }
    size_t xa_sz = (size_t)G * 4356 * 576 * 2;
    size_t xb_sz = (size_t)G * 4356 * 1664 * 2;

    char* ws = (char*)d_ws;
    bf16* Xa   = (bf16*)(ws);
    bf16* Xb   = (bf16*)(ws + xa_sz);
    bf16* Wcc  = (bf16*)(ws + xa_sz + xb_sz);
    bf16* Wdec = sepW ? (bf16*)(ws + xa_sz + xb_sz + wcc_sz) : Wcc;
    bf16* Wo1  = sepW ? (bf16*)(ws + xa_sz + xb_sz + wcc_sz + wsm_sz) : Wcc;
    size_t wtot = wcc_sz + (sepW ? 2 * wsm_sz : 0);
    float* sb  = (float*)(ws + xa_sz + xb_sz + wtot);
    float* invDec = sb,        *betaDec = sb + 576;
    float* invCc  = sb + 1152, *betaCc  = sb + 1728;
    float* invO1  = sb + 2304, *betaO1  = sb + 2880;
    float* smap = (float*)(ws + xa_sz + xb_sz + wtot + 16384);
    int* flag   = (int*)(ws + xa_sz + xb_sz + wtot + 16384 + 131072);
    bf16* Yo1q = Xb;

    detect_k<<<1, 64, 0, stream>>>(coarse, flag);
    scale_beta_k<<<3, 256, 0, stream>>>(dec_g, dec_b, dec_m, dec_v, flag, invDec, betaDec);
    scale_beta_k<<<3, 256, 0, stream>>>(cc_g, cc_b, cc_m, cc_v, flag, invCc, betaCc);
    scale_beta_k<<<3, 256, 0, stream>>>(o1_g, o1_b, o1_m, o1_v, flag, invO1, betaO1);
    if (sepW) {
        fold_w_k<<<dim3(3, 640, 9), 256, 0, stream>>>(dec_w, Wdec, flag, 576, 576, 1);
        fold_w_k<<<dim3(7, 640, 9), 256, 0, stream>>>(cc_w, Wcc, flag, 1632, 1664, 0);
        fold_w_k<<<dim3(3, 640, 9), 256, 0, stream>>>(o1_w, Wo1, flag, 576, 576, 0);
    }

    const int nchunk = 8 / G;
    const int mt = G * 16;                 // 256-row M-tiles per chunk
    for (int q = 0; q < nchunk; q++) {
        const int b0 = q * G;
        zero_border_k<<<dim3(260, G), 256, 0, stream>>>(Xa, 576);
        zero_border_k<<<dim3(260, G), 256, 0, stream>>>(Xb, 1664);
        zero_chanpad_k<<<(G * 4356 * 4 + 255) / 256, 256, 0, stream>>>(Xb, G * 4356 * 4);
        nchw_to_pnhwc_k<<<dim3(12, 64, G), 256, 0, stream>>>(coarse, Xa, flag, 384, 576, 0, b0);
        raw_patches_k<<<dim3(64, 3, G), 256, 0, stream>>>(rawx, Xa, flag, b0);
        nchw_to_pnhwc_k<<<dim3(24, 64, G), 256, 0, stream>>>(x22, Xb, flag, 768, 1664, 0, b0);
        nchw_to_pnhwc_k<<<dim3(9, 64, G), 256, 0, stream>>>(x31, Xb, flag, 288, 1664, 1344, b0);
        if (!sepW) fold_w_k<<<dim3(3, 640, 9), 256, 0, stream>>>(dec_w, Wdec, flag, 576, 576, 1);
        conv3x3_mfma<<<dim3(mt * 2), 512, 0, stream>>>(Xa, Wdec, invDec, betaDec, Xb, 576, 1664, 768, 1, mt);
        if (!sepW) fold_w_k<<<dim3(7, 640, 9), 256, 0, stream>>>(cc_w, Wcc, flag, 1632, 1664, 0);
        conv3x3_mfma<<<dim3(mt * 2), 512, 0, stream>>>(Xb, Wcc, invCc, betaCc, Xa, 1664, 576, 0, 1, mt);
        if (!sepW) fold_w_k<<<dim3(3, 640, 9), 256, 0, stream>>>(o1_w, Wo1, flag, 576, 576, 0);
        conv3x3_mfma<<<dim3(mt * 2), 512, 0, stream>>>(Xa, Wo1, invO1, betaO1, Yo1q, 576, 576, 0, 0, mt);
        o2_dot_k<<<G * 1024, 256, 0, stream>>>(Yo1q, o2_w, o2_b, flag, smap + (size_t)q * G * 4096);
    }
    upsample_k<<<8192, 256, 0, stream>>>(smap, d_out, flag);
}

// Round 5
// 1290.264 us; speedup vs baseline: 1.4464x; 1.0995x over previous
//
#include <hip/hip_runtime.h>
#include <hip/hip_bf16.h>
#include <stdint.h>

typedef __attribute__((ext_vector_type(8))) __bf16 bf16x8;
typedef __attribute__((ext_vector_type(8))) short short8;
typedef __attribute__((ext_vector_type(4))) float floatx4;
using bf16 = __hip_bfloat16;

#define DEVINL __device__ __forceinline__

typedef __attribute__((address_space(1))) const void gconst_void;
typedef __attribute__((address_space(3))) void lds_void;

DEVINL void gl2lds16(const void* g, void* l) {
    __builtin_amdgcn_global_load_lds((gconst_void*)g, (lds_void*)l, 16, 0, 0);
}

DEVINL unsigned short f2us(float x) {
    bf16 h = __float2bfloat16(x);
    return __builtin_bit_cast(unsigned short, h);
}
// flag==1: inputs are f32; flag==0: inputs are bf16
DEVINL float ld_in(const void* p, int f, size_t i) {
    return f ? ((const float*)p)[i] : __bfloat162float(((const bf16*)p)[i]);
}

// ---------------- dtype probe (confirmed: inputs are f32; keep hedge) ----------------
__global__ void detect_k(const void* x, int* flag) {
    if (threadIdx.x == 0) {
        const float* xf = (const float*)x;
        int good = 0;
        for (int i = 0; i < 64; i++) {
            float a = fabsf(xf[i]);
            if (a > 1e-8f && a < 100.f) good++;
        }
        *flag = (good >= 48) ? 1 : 0;
    }
}

// ---------------- prep kernels ----------------

__global__ void zero_border_k(bf16* buf, int C) {
    int cell = blockIdx.x;   // 0..259
    int b = blockIdx.y;
    int hp, wp;
    if (cell < 66)       { hp = 0;          wp = cell; }
    else if (cell < 132) { hp = 65;         wp = cell - 66; }
    else if (cell < 196) { hp = cell - 131; wp = 0; }
    else                 { hp = cell - 195; wp = 65; }
    unsigned short* p = (unsigned short*)buf + (size_t)(b * 4356 + hp * 66 + wp) * C;
    for (int c = threadIdx.x; c < C; c += 256) p[c] = 0;
}

// zero pad channels 1632..1663 of Xb for every cell (keeps MFMA inputs clean; weights there are 0)
__global__ void zero_chanpad_k(bf16* Xb, int n) {   // n = G*4356*4
    int idx = blockIdx.x * 256 + threadIdx.x;
    if (idx >= n) return;
    int cell = idx >> 2, sub = idx & 3;
    uint4 z; z.x = 0; z.y = 0; z.z = 0; z.w = 0;
    *(uint4*)((unsigned short*)Xb + (size_t)cell * 1664 + 1632 + sub * 8) = z;
}

__global__ void nchw_to_pnhwc_k(const void* __restrict__ src, bf16* __restrict__ dst,
                                const int* __restrict__ flag,
                                int Csrc, int dstC, int chanOff, int b0) {
    __shared__ unsigned short t[32][72];
    int c0 = blockIdx.x * 32, h = blockIdx.y, bz = blockIdx.z;
    int tid = threadIdx.x;
    {
        int c = tid >> 3, w8 = (tid & 7) * 8;
        size_t base = (((size_t)((b0 + bz) * Csrc + c0 + c)) * 64 + h) * 64 + w8;
        unsigned short* tp = &t[c][w8];
        if (*flag) {
            const float* sf = (const float*)src;
            float4 v0 = *(const float4*)(sf + base);
            float4 v1 = *(const float4*)(sf + base + 4);
            tp[0] = f2us(v0.x); tp[1] = f2us(v0.y); tp[2] = f2us(v0.z); tp[3] = f2us(v0.w);
            tp[4] = f2us(v1.x); tp[5] = f2us(v1.y); tp[6] = f2us(v1.z); tp[7] = f2us(v1.w);
        } else {
            uint4 v = *(const uint4*)((const unsigned short*)src + base);
            *(uint4*)tp = v;
        }
    }
    __syncthreads();
    {
        int w = tid >> 2, cq = (tid & 3) * 8;
        uint32_t p0 = t[cq + 0][w] | ((uint32_t)t[cq + 1][w] << 16);
        uint32_t p1 = t[cq + 2][w] | ((uint32_t)t[cq + 3][w] << 16);
        uint32_t p2 = t[cq + 4][w] | ((uint32_t)t[cq + 5][w] << 16);
        uint32_t p3 = t[cq + 6][w] | ((uint32_t)t[cq + 7][w] << 16);
        uint4 o; o.x = p0; o.y = p1; o.z = p2; o.w = p3;
        size_t off = ((size_t)(bz * 4356 + (h + 1) * 66 + (w + 1))) * dstC + chanOff + c0 + cq;
        *(uint4*)((unsigned short*)dst + off) = o;
    }
}

__global__ void raw_patches_k(const void* __restrict__ raw, bf16* __restrict__ Xa,
                              const int* __restrict__ flag, int b0) {
    __shared__ unsigned short t[8][520];
    int h = blockIdx.x, craw = blockIdx.y, bz = blockIdx.z;
    int tid = threadIdx.x;
    int f = *flag;
#pragma unroll
    for (int k = 0; k < 2; k++) {
        int s = tid + k * 256;
        int gy = s >> 6, seg = s & 63;
        size_t base = (((size_t)((b0 + bz) * 3 + craw) * 512) + gy * 64 + h) * 512 + seg * 8;
        unsigned short* tp = &t[gy][seg * 8];
        if (f) {
            const float* rf = (const float*)raw;
            float4 v0 = *(const float4*)(rf + base);
            float4 v1 = *(const float4*)(rf + base + 4);
            tp[0] = f2us(v0.x); tp[1] = f2us(v0.y); tp[2] = f2us(v0.z); tp[3] = f2us(v0.w);
            tp[4] = f2us(v1.x); tp[5] = f2us(v1.y); tp[6] = f2us(v1.z); tp[7] = f2us(v1.w);
        } else {
            uint4 v = *(const uint4*)((const unsigned short*)raw + base);
            *(uint4*)tp = v;
        }
    }
    __syncthreads();
#pragma unroll
    for (int k = 0; k < 2; k++) {
        int s = tid + k * 256;
        int w = s >> 3, gq = s & 7;
        uint32_t p0 = t[gq][0 * 64 + w] | ((uint32_t)t[gq][1 * 64 + w] << 16);
        uint32_t p1 = t[gq][2 * 64 + w] | ((uint32_t)t[gq][3 * 64 + w] << 16);
        uint32_t p2 = t[gq][4 * 64 + w] | ((uint32_t)t[gq][5 * 64 + w] << 16);
        uint32_t p3 = t[gq][6 * 64 + w] | ((uint32_t)t[gq][7 * 64 + w] << 16);
        uint4 o; o.x = p0; o.y = p1; o.z = p2; o.w = p3;
        size_t off = ((size_t)(bz * 4356 + (h + 1) * 66 + (w + 1))) * 576 + 384 + craw * 64 + gq * 8;
        *(uint4*)((unsigned short*)Xa + off) = o;
    }
}

// srcC = real input channels of the torch weight; dstC = padded K-stride of folded buffer.
// Output rows padded to 640 (rows 576..639 zero) -> 2 exact BN=320 tiles.
__global__ void fold_w_k(const void* __restrict__ W, bf16* __restrict__ dst,
                         const int* __restrict__ flag, int srcC, int dstC, int remap) {
    int ci = blockIdx.x * 256 + threadIdx.x;
    if (ci >= dstC) return;
    int co = blockIdx.y;  // 0..639
    int kk = blockIdx.z;  // 0..8
    unsigned short out = 0;
    if (co < 576 && ci < srcC) {
        int oc = ci;
        if (remap && ci >= 384) {
            int tt = ci - 384;
            int craw = tt >> 6, gy = (tt >> 3) & 7, gx = tt & 7;
            oc = 384 + gy * 24 + gx * 3 + craw;
        }
        size_t sidx = ((size_t)co * srcC + oc) * 9 + kk;
        out = (*flag) ? f2us(((const float*)W)[sidx]) : ((const unsigned short*)W)[sidx];
    }
    ((unsigned short*)dst)[((size_t)kk * 640 + co) * dstC + ci] = out;
}

__global__ void scale_beta_k(const void* g, const void* b, const void* m, const void* v,
                             const int* __restrict__ flag, float* inv_out, float* beta_out) {
    int i = blockIdx.x * 256 + threadIdx.x;
    int f = *flag;
    if (i < 576) {
        float inv = ld_in(g, f, i) / sqrtf(ld_in(v, f, i) + 1e-5f);
        inv_out[i] = inv;
        beta_out[i] = ld_in(b, f, i) - ld_in(m, f, i) * inv;
    }
}

// ---------------- 3x3 conv, implicit GEMM, 2-barrier double-buffer pipeline ----------------
// BM=256 BN=320 BK=64, 512 thr / 8 waves (2M x 4N, wave tile 128x80, acc 8x5).
// r5 change vs r4 (single variable): the 6 intra-tile barriers are REMOVED -- only
// the two required by the double-buffer invariants remain per K-tile:
//   (1) validity barrier after the counted vmcnt(3)  (all waves staged tile t)
//   (2) end-of-tile barrier                          (reads of buf p done before
//                                                     iteration t+1 re-stages p)
// r4's 8 lockstep barriers serialized LDS-read windows against MFMA windows
// (measured 6525 cyc/K-tile vs 2960 MFMA floor, MfmaUtil 43%). With the whole
// 26-read / 80-MFMA / 6-stage body visible, the compiler emits fine-grained
// lgkmcnt interleave (m97 evidence) and wave skew overlaps reads with MFMA.
// Counted vmcnt(3) never drains in steady state (T3/T4). T2 XOR swizzle
// both-sides (0 conflicts, verified r1-r4). T5 setprio. T1 XCD swizzle.
__global__ __launch_bounds__(512, 2)
void conv3x3_mfma(const bf16* __restrict__ X, const bf16* __restrict__ Wp,
                  const float* __restrict__ inv, const float* __restrict__ beta,
                  bf16* __restrict__ dst, int Cin, int dstC, int chanOff, int dstPadded,
                  int mtiles) {
    __shared__ __align__(16) bf16 Alds[2 * 16384];   // 2 x 32 KB : [256 rows][64]
    __shared__ __align__(16) bf16 Blds[2 * 20480];   // 2 x 40 KB : [320 rows][64]
    const int tid = threadIdx.x;
    const int wv = tid >> 6;
    const int lane = tid & 63;
    const int quad = lane >> 4;
    const int r16 = lane & 15;

    // T1: XCD-contiguous remap (nwg = 32*G, always % 8 == 0)
    const int nwg = gridDim.x;
    const int wg = ((int)blockIdx.x & 7) * (nwg >> 3) + ((int)blockIdx.x >> 3);
    const int m0 = (wg % mtiles) * 256;
    const int n0 = (wg / mtiles) * 320;

    // staging: each 64-row chunk = 8 KB = one gl2lds across 512 threads
    const int rl = tid >> 3;                          // 0..63 (row within chunk)
    const int cg = ((tid & 7) ^ (rl & 7)) * 8;        // inverse-swizzled source chunk (halfwords)
    int aF[4], bF[5];
#pragma unroll
    for (int q = 0; q < 4; q++) {
        int r = m0 + q * 64 + rl;
        int bb = r >> 12, hh = (r >> 6) & 63;
        aF[q] = (bb * 4356 + (hh + 1) * 66 + (rl + 1)) * Cin + cg;
    }
#pragma unroll
    for (int q = 0; q < 5; q++) bF[q] = (n0 + q * 64 + rl) * Cin + cg;

    // fragment-read geometry (wave tile 128x80: 8 M-frags x 5 N-frags)
    const int wvM = wv >> 2, wvN = wv & 3;
    int aOff[8], bOff[5];
#pragma unroll
    for (int i = 0; i < 8; i++) aOff[i] = (wvM * 128 + i * 16 + r16) * 64;
#pragma unroll
    for (int j = 0; j < 5; j++) bOff[j] = (wvN * 80 + j * 16 + r16) * 64;
    const int sw0 = (quad ^ (r16 & 7)) * 8;           // swizzled chunk, kq=0
    const int sw1 = ((quad + 4) ^ (r16 & 7)) * 8;     // swizzled chunk, kq=1

    floatx4 acc[8][5];
    floatx4 zero = {0.f, 0.f, 0.f, 0.f};
#pragma unroll
    for (int i = 0; i < 8; i++)
#pragma unroll
        for (int j = 0; j < 5; j++) acc[i][j] = zero;

#define BAR() asm volatile("s_barrier" ::: "memory")
#define READB(sw) do { \
    _Pragma("unroll") for (int j_ = 0; j_ < 5; j_++) \
        bfr[j_] = *(const short8*)(Bp + bOff[j_] + (sw)); } while (0)
#define READA(h, sw) do { \
    _Pragma("unroll") for (int i_ = 0; i_ < 4; i_++) \
        af[i_] = *(const short8*)(Ap + aOff[(h) * 4 + i_] + (sw)); } while (0)
#define MM(h) do { \
    __builtin_amdgcn_s_setprio(1); \
    _Pragma("unroll") for (int i_ = 0; i_ < 4; i_++) \
    _Pragma("unroll") for (int j_ = 0; j_ < 5; j_++) \
        acc[(h) * 4 + i_][j_] = __builtin_amdgcn_mfma_f32_16x16x32_bf16( \
            __builtin_bit_cast(bf16x8, af[i_]), __builtin_bit_cast(bf16x8, bfr[j_]), \
            acc[(h) * 4 + i_][j_], 0, 0, 0); \
    __builtin_amdgcn_s_setprio(0); } while (0)
#define GA(q) gl2lds16(X + aF[q] + so, Ao + (q) * 4096 + wv * 512)
#define GB(q) gl2lds16(Wp + bF[q] + wo, Bo + (q) * 4096 + wv * 512)
#define ADV() do { ciN += 64; if (ciN == Cin) { ciN = 0; ++kkN; \
        tapOffN = ((kkN / 3) * 66 + (kkN % 3) - 67) * Cin; wbN += 640 * Cin; } } while (0)

    // flat K bookkeeping: (kkN, ciN) = coordinates of the NEXT tile to stage
    int kkN = 0, ciN = 0, tapOffN = -67 * Cin, wbN = 0;   // tap 0: dh=-1,dw=-1
    {   // prologue: stage tile 0 fully into buf 0
        const int so = tapOffN + ciN, wo = wbN + ciN;
        bf16* Ao = Alds; bf16* Bo = Blds;
        GA(0); GA(1); GA(2); GA(3);
        GB(0); GB(1); GB(2); GB(3); GB(4);
    }
    ADV();
    const int NT = 9 * (Cin >> 6);
    int p = 0;
    for (int t = 0; t < NT - 1; ++t, p ^= 1) {
        const bf16* Ap = Alds + p * 16384;
        const bf16* Bp = Blds + p * 20480;
        bf16* Ao = Alds + (p ^ 1) * 16384;
        bf16* Bo = Blds + (p ^ 1) * 20480;
        const int so = tapOffN + ciN, wo = wbN + ciN;
        short8 af[4], bfr[5];
        // stage first 3 chunks of tile t+1, counted wait for tile t, validity barrier
        GA(0); GA(1); GA(2);
        asm volatile("s_waitcnt vmcnt(3)" ::: "memory");
        BAR();
        // whole K-tile body: no intra-tile barriers; compiler interleaves
        // ds_reads / gl2lds issues under the MFMA clusters (fine lgkmcnt)
        READB(sw0); READA(0, sw0);
        MM(0);
        READA(1, sw0);
        GA(3); GB(0); GB(1);
        MM(1);
        READB(sw1); READA(0, sw1);
        GB(2); GB(3); GB(4);
        MM(0);
        READA(1, sw1);
        MM(1);
        BAR();   // reads of buf p complete -> iteration t+1 may re-stage p
        ADV();
    }
    {   // last tile: nothing newer outstanding -> one-time full drain
        const bf16* Ap = Alds + p * 16384;
        const bf16* Bp = Blds + p * 20480;
        short8 af[4], bfr[5];
        asm volatile("s_waitcnt vmcnt(0)" ::: "memory");
        BAR();
        READB(sw0); READA(0, sw0); MM(0);
        READA(1, sw0); MM(1);
        READB(sw1); READA(0, sw1); MM(0);
        READA(1, sw1); MM(1);
    }
#undef BAR
#undef READB
#undef READA
#undef MM
#undef GA
#undef GB
#undef ADV

    // epilogue (loads kept OUT of the loop so vmcnt counting stays exact):
    // D[row=quad*4+r, col=lane&15] (verified m89/m91 layout)
    int ncol[5]; float sj[5], bj[5]; bool nval[5];
#pragma unroll
    for (int j = 0; j < 5; j++) {
        ncol[j] = n0 + wvN * 80 + j * 16 + r16;
        nval[j] = ncol[j] < 576;
        sj[j] = nval[j] ? inv[ncol[j]] : 0.f;
        bj[j] = nval[j] ? beta[ncol[j]] : 0.f;
    }
#pragma unroll
    for (int i = 0; i < 8; i++) {
#pragma unroll
        for (int r = 0; r < 4; r++) {
            int row = m0 + wvM * 128 + i * 16 + quad * 4 + r;
            int didx;
            if (dstPadded) {
                int bb = row >> 12, hh = (row >> 6) & 63, ww = row & 63;
                didx = (bb * 4356 + (hh + 1) * 66 + (ww + 1)) * dstC + chanOff;
            } else {
                didx = row * dstC + chanOff;
            }
#pragma unroll
            for (int j = 0; j < 5; j++)
                if (nval[j]) dst[didx + ncol[j]] = __float2bfloat16(acc[i][j][r] * sj[j] + bj[j]);
        }
    }
}

// ---------------- tail: 1x1 conv (576->1) + x8 bilinear upsample ----------------
__global__ void o2_dot_k(const bf16* __restrict__ Y, const void* __restrict__ w,
                         const void* __restrict__ bias, const int* __restrict__ flag,
                         float* __restrict__ smap) {
    __shared__ float wl[576];
    int tid = threadIdx.x;
    int f = *flag;
    for (int c = tid; c < 576; c += 256) wl[c] = ld_in(w, f, c);
    __syncthreads();
    int wv = tid >> 6, lane = tid & 63;
    int pix = blockIdx.x * 4 + wv;
    const bf16* yp = Y + (size_t)pix * 576;
    float s = 0.f;
#pragma unroll
    for (int k = 0; k < 9; k++) {
        int c = k * 64 + lane;
        s += __bfloat162float(yp[c]) * wl[c];
    }
#pragma unroll
    for (int off = 32; off; off >>= 1) s += __shfl_xor(s, off, 64);
    if (lane == 0) smap[pix] = s + ld_in(bias, f, 0);
}

__global__ void upsample_k(const float* __restrict__ smap, void* __restrict__ out,
                           const int* __restrict__ flag) {
    int idx = blockIdx.x * 256 + threadIdx.x;   // 8*512*512 exact
    int b = idx >> 18;
    int ho = (idx >> 9) & 511;
    int wo = idx & 511;
    const float sc = 63.f / 511.f;              // align_corners=True
    float ys = ho * sc, xs = wo * sc;
    int y0 = (int)ys; float ty = ys - y0; int y1 = min(y0 + 1, 63);
    int x0 = (int)xs; float tx = xs - x0; int x1 = min(x0 + 1, 63);
    const float* sp = smap + (b << 12);
    float r0 = sp[y0 * 64 + x0] * (1.f - tx) + sp[y0 * 64 + x1] * tx;
    float r1 = sp[y1 * 64 + x0] * (1.f - tx) + sp[y1 * 64 + x1] * tx;
    float val = r0 * (1.f - ty) + r1 * ty;
    if (*flag) ((float*)out)[idx] = val;
    else       ((bf16*)out)[idx] = __float2bfloat16(val);
}

// ---------------- launch ----------------
extern "C" void kernel_launch(void* const* d_in, const int* in_sizes, int n_in,
                              void* d_out, int out_size, void* d_ws, size_t ws_size,
                              hipStream_t stream) {
    const void* coarse = d_in[0];
    const void* x22    = d_in[1];
    const void* x31    = d_in[2];
    const void* rawx   = d_in[3];
    // d_in[4]=w_pred, d_in[5]=b_pred : dead code in reference
    const void* dec_w = d_in[6];
    const void *dec_g = d_in[7], *dec_b = d_in[8], *dec_m = d_in[9], *dec_v = d_in[10];
    const void* cc_w = d_in[11];
    const void *cc_g = d_in[12], *cc_b = d_in[13], *cc_m = d_in[14], *cc_v = d_in[15];
    const void* o1_w = d_in[16];
    const void *o1_g = d_in[17], *o1_b = d_in[18], *o1_m = d_in[19], *o1_v = d_in[20];
    const void* o2_w = d_in[21];
    const void* o2_b = d_in[22];

    // adaptive chunk ladder (weights: 640 output rows; cc K-pad 1632->1664)
    const size_t wcc_sz  = (size_t)9 * 640 * 1664 * 2;
    const size_t wsm_sz  = (size_t)9 * 640 * 576 * 2;
    const size_t tail_sz = 16384 + 131072 + 256;
    int G = 8; int sepW = 1;
    for (;;) {
        size_t acts = (size_t)G * 4356 * (576 + 1664) * 2;
        if (acts + wcc_sz + 2 * wsm_sz + tail_sz <= ws_size) { sepW = 1; break; }
        if (acts + wcc_sz + tail_sz <= ws_size)              { sepW = 0; break; }
        if (G == 1) { sepW = 0; break; }
        G >>= 1;
    }
    size_t xa_sz = (size_t)G * 4356 * 576 * 2;
    size_t xb_sz = (size_t)G * 4356 * 1664 * 2;

    char* ws = (char*)d_ws;
    bf16* Xa   = (bf16*)(ws);
    bf16* Xb   = (bf16*)(ws + xa_sz);
    bf16* Wcc  = (bf16*)(ws + xa_sz + xb_sz);
    bf16* Wdec = sepW ? (bf16*)(ws + xa_sz + xb_sz + wcc_sz) : Wcc;
    bf16* Wo1  = sepW ? (bf16*)(ws + xa_sz + xb_sz + wcc_sz + wsm_sz) : Wcc;
    size_t wtot = wcc_sz + (sepW ? 2 * wsm_sz : 0);
    float* sb  = (float*)(ws + xa_sz + xb_sz + wtot);
    float* invDec = sb,        *betaDec = sb + 576;
    float* invCc  = sb + 1152, *betaCc  = sb + 1728;
    float* invO1  = sb + 2304, *betaO1  = sb + 2880;
    float* smap = (float*)(ws + xa_sz + xb_sz + wtot + 16384);
    int* flag   = (int*)(ws + xa_sz + xb_sz + wtot + 16384 + 131072);
    bf16* Yo1q = Xb;

    detect_k<<<1, 64, 0, stream>>>(coarse, flag);
    scale_beta_k<<<3, 256, 0, stream>>>(dec_g, dec_b, dec_m, dec_v, flag, invDec, betaDec);
    scale_beta_k<<<3, 256, 0, stream>>>(cc_g, cc_b, cc_m, cc_v, flag, invCc, betaCc);
    scale_beta_k<<<3, 256, 0, stream>>>(o1_g, o1_b, o1_m, o1_v, flag, invO1, betaO1);
    if (sepW) {
        fold_w_k<<<dim3(3, 640, 9), 256, 0, stream>>>(dec_w, Wdec, flag, 576, 576, 1);
        fold_w_k<<<dim3(7, 640, 9), 256, 0, stream>>>(cc_w, Wcc, flag, 1632, 1664, 0);
        fold_w_k<<<dim3(3, 640, 9), 256, 0, stream>>>(o1_w, Wo1, flag, 576, 576, 0);
    }

    const int nchunk = 8 / G;
    const int mt = G * 16;                 // 256-row M-tiles per chunk
    for (int q = 0; q < nchunk; q++) {
        const int b0 = q * G;
        zero_border_k<<<dim3(260, G), 256, 0, stream>>>(Xa, 576);
        zero_border_k<<<dim3(260, G), 256, 0, stream>>>(Xb, 1664);
        zero_chanpad_k<<<(G * 4356 * 4 + 255) / 256, 256, 0, stream>>>(Xb, G * 4356 * 4);
        nchw_to_pnhwc_k<<<dim3(12, 64, G), 256, 0, stream>>>(coarse, Xa, flag, 384, 576, 0, b0);
        raw_patches_k<<<dim3(64, 3, G), 256, 0, stream>>>(rawx, Xa, flag, b0);
        nchw_to_pnhwc_k<<<dim3(24, 64, G), 256, 0, stream>>>(x22, Xb, flag, 768, 1664, 0, b0);
        nchw_to_pnhwc_k<<<dim3(9, 64, G), 256, 0, stream>>>(x31, Xb, flag, 288, 1664, 1344, b0);
        if (!sepW) fold_w_k<<<dim3(3, 640, 9), 256, 0, stream>>>(dec_w, Wdec, flag, 576, 576, 1);
        conv3x3_mfma<<<dim3(mt * 2), 512, 0, stream>>>(Xa, Wdec, invDec, betaDec, Xb, 576, 1664, 768, 1, mt);
        if (!sepW) fold_w_k<<<dim3(7, 640, 9), 256, 0, stream>>>(cc_w, Wcc, flag, 1632, 1664, 0);
        conv3x3_mfma<<<dim3(mt * 2), 512, 0, stream>>>(Xb, Wcc, invCc, betaCc, Xa, 1664, 576, 0, 1, mt);
        if (!sepW) fold_w_k<<<dim3(3, 640, 9), 256, 0, stream>>>(o1_w, Wo1, flag, 576, 576, 0);
        conv3x3_mfma<<<dim3(mt * 2), 512, 0, stream>>>(Xa, Wo1, invO1, betaO1, Yo1q, 576, 576, 0, 0, mt);
        o2_dot_k<<<G * 1024, 256, 0, stream>>>(Yo1q, o2_w, o2_b, flag, smap + (size_t)q * G * 4096);
    }
    upsample_k<<<8192, 256, 0, stream>>>(smap, d_out, flag);
}